// Round 1
// baseline (203.469 us; speedup 1.0000x reference)
//
#include <hip/hip_runtime.h>
#include <hip/hip_bf16.h>
#include <math.h>

// Problem constants
#define B_   2
#define N_   8192
#define D_   256
#define C_   6
#define HF_  64
#define WF_  64
#define P_   4
#define BN_  (B_ * N_)   // 16384

__device__ __forceinline__ float wred64(float v) {
#pragma unroll
  for (int o = 32; o > 0; o >>= 1) v += __shfl_xor(v, o, 64);
  return v;
}

// ---------------------------------------------------------------------------
// Precompute A = Wq^T Wk  (A[i][j] = sum_o Wq[o][i] Wk[o][j])
// and B2T[e][d] = (Wo Wv)[d][e] = sum_m Wv[m][e] Wo[d][m]
// ---------------------------------------------------------------------------
__global__ __launch_bounds__(256) void k_prec_mats(
    const float* __restrict__ Wq, const float* __restrict__ Wk,
    const float* __restrict__ Wv, const float* __restrict__ Wo,
    float* __restrict__ A, float* __restrict__ B2T) {
  const int i = threadIdx.x;
  const int blk = blockIdx.x;
  if (blk < 256) {
    const int j = blk;
    float acc = 0.f;
    for (int m = 0; m < 256; ++m) acc += Wq[m * 256 + i] * Wk[m * 256 + j];
    A[i * 256 + j] = acc;
  } else {
    const int d = blk - 256;
    float acc = 0.f;
    for (int m = 0; m < 256; ++m) acc += Wv[m * 256 + i] * Wo[d * 256 + m];
    B2T[i * 256 + d] = acc;
  }
}

// vec2 = Wq^T bk ; vec1 = Wk^T bq ; beta = Wo bv ; bqbk = bq.bk
__global__ __launch_bounds__(256) void k_prec_vecs(
    const float* __restrict__ Wq, const float* __restrict__ bk,
    const float* __restrict__ Wk, const float* __restrict__ bq,
    const float* __restrict__ Wo, const float* __restrict__ bv,
    float* __restrict__ vec1, float* __restrict__ vec2,
    float* __restrict__ beta, float* __restrict__ bqbk) {
  const int i = threadIdx.x;
  float a2 = 0.f, a1 = 0.f, ab = 0.f;
  for (int m = 0; m < 256; ++m) {
    a2 += Wq[m * 256 + i] * bk[m];
    a1 += Wk[m * 256 + i] * bq[m];
    ab += Wo[i * 256 + m] * bv[m];
  }
  vec2[i] = a2;
  vec1[i] = a1;
  beta[i] = ab;
  if (i == 0) {
    float s = 0.f;
    for (int m = 0; m < 256; ++m) s += bq[m] * bk[m];
    *bqbk = s;
  }
}

// ---------------------------------------------------------------------------
// LayerNorm + offsets (Woff proj *0.05) + gamma = vec2.qn + bqbk
// One wave per row; 4 rows per 256-thread block.
// ---------------------------------------------------------------------------
__global__ __launch_bounds__(256) void k_ln(
    const float* __restrict__ Q, const float* __restrict__ ln_g,
    const float* __restrict__ ln_b, const float* __restrict__ Woff,
    const float* __restrict__ boff, const float* __restrict__ vec2,
    const float* __restrict__ bqbk, float* __restrict__ QN,
    float* __restrict__ OFFS, float* __restrict__ GAM) {
  const int wave = threadIdx.x >> 6, lane = threadIdx.x & 63;
  const int m = blockIdx.x * 4 + wave;
  const int base = m * 256 + lane * 4;
  const float4 x = *(const float4*)&Q[base];
  float s = x.x + x.y + x.z + x.w;
  float sq = x.x * x.x + x.y * x.y + x.z * x.z + x.w * x.w;
  s = wred64(s);
  sq = wred64(sq);
  const float mu = s * (1.0f / 256.0f);
  const float var = sq * (1.0f / 256.0f) - mu * mu;
  const float rs = rsqrtf(var + 1e-5f);
  const float4 g = *(const float4*)&ln_g[lane * 4];
  const float4 bb = *(const float4*)&ln_b[lane * 4];
  float4 y;
  y.x = (x.x - mu) * rs * g.x + bb.x;
  y.y = (x.y - mu) * rs * g.y + bb.y;
  y.z = (x.z - mu) * rs * g.z + bb.z;
  y.w = (x.w - mu) * rs * g.w + bb.w;
  *(float4*)&QN[base] = y;
  const float4 v2 = *(const float4*)&vec2[lane * 4];
  float gp = wred64(v2.x * y.x + v2.y * y.y + v2.z * y.z + v2.w * y.w);
  if (lane == 0) GAM[m] = gp + bqbk[0];
#pragma unroll
  for (int p2 = 0; p2 < 8; ++p2) {
    const float4 w = *(const float4*)&Woff[p2 * 256 + lane * 4];
    const float o = wred64(w.x * y.x + w.y * y.y + w.z * y.z + w.w * y.w);
    if (lane == 0) OFFS[m * 8 + p2] = (o + boff[p2]) * 0.05f;
  }
}

// ---------------------------------------------------------------------------
// Tiled f32 GEMM: Y[M x 256] = X[M x 256] @ W[256 x 256]  (+ epilogue)
// MODE 0: Y += cvec[j]          (T = QN@A + vec1)
// MODE 1: Y += resid + wscale[row]*beta[j] + bo[j]   (final output)
// 64x64 tile per block, 16x16 threads, 4x4 micro-tile, KC=8.
// ---------------------------------------------------------------------------
template <int MODE>
__global__ __launch_bounds__(256) void k_gemm256(
    const float* __restrict__ X, const float* __restrict__ W,
    float* __restrict__ Y, const float* __restrict__ cvec,
    const float* __restrict__ resid, const float* __restrict__ wscale,
    const float* __restrict__ beta, const float* __restrict__ bo) {
  __shared__ float As[8][64];  // As[k][m]
  __shared__ float Bs[8][64];  // Bs[k][n]
  const int t = threadIdx.x;
  const int nb = blockIdx.x & 3;
  const int mb = blockIdx.x >> 2;
  const int m0 = mb * 64, n0 = nb * 64;
  const int tx = t & 15, ty = t >> 4;
  float acc[4][4] = {};
  for (int k0 = 0; k0 < 256; k0 += 8) {
    {
      int e = t;
      int i = e >> 3, j = e & 7;
      As[j][i] = X[(m0 + i) * 256 + k0 + j];
      e = t + 256;
      i = e >> 3;
      j = e & 7;
      As[j][i] = X[(m0 + i) * 256 + k0 + j];
      const int k = t >> 6, n = t & 63;
      Bs[k][n] = W[(k0 + k) * 256 + n0 + n];
      Bs[k + 4][n] = W[(k0 + k + 4) * 256 + n0 + n];
    }
    __syncthreads();
#pragma unroll
    for (int kk = 0; kk < 8; ++kk) {
      const float4 a = *(const float4*)&As[kk][ty * 4];
      const float4 b = *(const float4*)&Bs[kk][tx * 4];
      const float av[4] = {a.x, a.y, a.z, a.w};
      const float bv4[4] = {b.x, b.y, b.z, b.w};
#pragma unroll
      for (int r = 0; r < 4; ++r)
#pragma unroll
        for (int c = 0; c < 4; ++c) acc[r][c] += av[r] * bv4[c];
    }
    __syncthreads();
  }
#pragma unroll
  for (int r = 0; r < 4; ++r) {
    const int row = m0 + ty * 4 + r;
    const int col = n0 + tx * 4;
    float4 o = {acc[r][0], acc[r][1], acc[r][2], acc[r][3]};
    if (MODE == 0) {
      const float4 cv = *(const float4*)&cvec[col];
      o.x += cv.x;
      o.y += cv.y;
      o.z += cv.z;
      o.w += cv.w;
    } else {
      const float4 rv = *(const float4*)&resid[row * 256 + col];
      const float4 bt = *(const float4*)&beta[col];
      const float4 bv4 = *(const float4*)&bo[col];
      const float wsc = wscale[row];
      o.x += rv.x + wsc * bt.x + bv4.x;
      o.y += rv.y + wsc * bt.y + bv4.y;
      o.z += rv.z + wsc * bt.z + bv4.z;
      o.w += rv.w + wsc * bt.w + bv4.w;
    }
    *(float4*)&Y[row * 256 + col] = o;
  }
}

// ---------------------------------------------------------------------------
// Fused bilinear sampling + scores + weighted aggregation.
// One wave per (b,n); loops c=0..5; skips invalid cameras entirely.
// SV[m][:] = (sum_c w_c * sbar_c) / tw ; wscale[m] = (sum_c w_c) / tw
// ---------------------------------------------------------------------------
__global__ __launch_bounds__(256) void k_sample(
    const float* __restrict__ feats, const float* __restrict__ pix,
    const int* __restrict__ vmask, const float* __restrict__ T,
    const float* __restrict__ GAM, const float* __restrict__ OFFS,
    float* __restrict__ SV, float* __restrict__ wscale) {
  const int wave = threadIdx.x >> 6, lane = threadIdx.x & 63;
  const int m = blockIdx.x * 4 + wave;
  const int b = m >> 13, n = m & 8191;
  const float4 t4 = *(const float4*)&T[m * 256 + lane * 4];
  const float gam = GAM[m];
  float offv[8];
#pragma unroll
  for (int p2 = 0; p2 < 8; ++p2) offv[p2] = OFFS[m * 8 + p2];
  float4 sv = {0.f, 0.f, 0.f, 0.f};
  float wsum = 0.f;
  int vcnt = 0;
  for (int c = 0; c < 6; ++c) {
    const int idx = (b * 6 + c) * 8192 + n;
    if (vmask[idx] == 0) continue;
    ++vcnt;
    const float pcx = pix[idx * 2 + 0];
    const float pcy = pix[idx * 2 + 1];
    const float* fb = feats + (size_t)(b * 6 + c) * (HF_ * WF_ * 256);
    float4 sm = {0.f, 0.f, 0.f, 0.f};
#pragma unroll
    for (int p = 0; p < 4; ++p) {
      const float gx = pcx + offv[2 * p];
      const float gy = pcy + offv[2 * p + 1];
      const float fx = (gx + 1.f) * 0.5f * 63.f;
      const float fy = (gy + 1.f) * 0.5f * 63.f;
      const float x0 = floorf(fx), y0 = floorf(fy);
      const float wx1 = fx - x0, wx0 = 1.f - wx1;
      const float wy1 = fy - y0, wy0 = 1.f - wy1;
#pragma unroll
      for (int cy = 0; cy < 2; ++cy) {
        const float yy = y0 + (float)cy;
        const float wy = cy ? wy1 : wy0;
        if (yy < 0.f || yy > 63.f || wy == 0.f) continue;
#pragma unroll
        for (int cx = 0; cx < 2; ++cx) {
          const float xx = x0 + (float)cx;
          const float wc = wy * (cx ? wx1 : wx0);
          if (xx < 0.f || xx > 63.f || wc == 0.f) continue;
          const int ri = (int)yy * WF_ + (int)xx;
          const float4 f4 = *(const float4*)&fb[(size_t)ri * 256 + lane * 4];
          sm.x += wc * f4.x;
          sm.y += wc * f4.y;
          sm.z += wc * f4.z;
          sm.w += wc * f4.w;
        }
      }
    }
    sm.x *= 0.25f;
    sm.y *= 0.25f;
    sm.z *= 0.25f;
    sm.w *= 0.25f;
    const float sc =
        wred64(t4.x * sm.x + t4.y * sm.y + t4.z * sm.z + t4.w * sm.w) + gam;
    const float w = sc * (1.f / 16.f);
    sv.x += w * sm.x;
    sv.y += w * sm.y;
    sv.z += w * sm.z;
    sv.w += w * sm.w;
    wsum += w;
  }
  const float tw = fmaxf((float)vcnt, 1.f);
  const float inv = 1.f / tw;
  const float4 o = {sv.x * inv, sv.y * inv, sv.z * inv, sv.w * inv};
  *(float4*)&SV[m * 256 + lane * 4] = o;
  if (lane == 0) wscale[m] = wsum * inv;
}

// ---------------------------------------------------------------------------
extern "C" void kernel_launch(void* const* d_in, const int* in_sizes, int n_in,
                              void* d_out, int out_size, void* d_ws,
                              size_t ws_size, hipStream_t stream) {
  const float* queries = (const float*)d_in[0];
  const float* feats = (const float*)d_in[1];
  const float* pix = (const float*)d_in[2];
  const int* vmask = (const int*)d_in[3];
  const float* Wq = (const float*)d_in[4];
  const float* bq = (const float*)d_in[5];
  const float* Wk = (const float*)d_in[6];
  const float* bk = (const float*)d_in[7];
  const float* Wv = (const float*)d_in[8];
  const float* bv = (const float*)d_in[9];
  const float* Wo = (const float*)d_in[10];
  const float* bo = (const float*)d_in[11];
  const float* Woff = (const float*)d_in[12];
  const float* boff = (const float*)d_in[13];
  const float* ln_g = (const float*)d_in[14];
  const float* ln_b = (const float*)d_in[15];

  float* ws = (float*)d_ws;
  // workspace layout (floats); total ~4.49M floats (~18 MB)
  float* A = ws + 0;               // 65536
  float* B2T = ws + 65536;         // 65536
  float* vec1 = ws + 131072;       // 256
  float* vec2 = ws + 131328;       // 256
  float* beta = ws + 131584;       // 256
  float* bqbk = ws + 131840;       // 16
  float* QN = ws + 131856;         // BN*256  (reused as nothing else; SV overlays it)
  float* OFFS = QN + BN_ * 256;    // BN*8
  float* GAM = OFFS + BN_ * 8;     // BN
  float* WSC = GAM + BN_;          // BN
  float* T = (float*)d_out;        // reuse d_out for T (freed before final GEMM)
  float* SV = QN;                  // QN no longer needed after GEMM1
  float* out = (float*)d_out;

  k_prec_mats<<<512, 256, 0, stream>>>(Wq, Wk, Wv, Wo, A, B2T);
  k_prec_vecs<<<1, 256, 0, stream>>>(Wq, bk, Wk, bq, Wo, bv, vec1, vec2, beta,
                                     bqbk);
  k_ln<<<BN_ / 4, 256, 0, stream>>>(queries, ln_g, ln_b, Woff, boff, vec2, bqbk,
                                    QN, OFFS, GAM);
  k_gemm256<0><<<(BN_ / 64) * 4, 256, 0, stream>>>(QN, A, T, vec1, nullptr,
                                                   nullptr, nullptr, nullptr);
  k_sample<<<BN_ / 4, 256, 0, stream>>>(feats, pix, vmask, T, GAM, OFFS, SV,
                                        WSC);
  k_gemm256<1><<<(BN_ / 64) * 4, 256, 0, stream>>>(SV, B2T, out, nullptr,
                                                   queries, WSC, beta, bo);
}

// Round 2
// 135.550 us; speedup vs baseline: 1.5011x; 1.5011x over previous
//
#include <hip/hip_runtime.h>
#include <hip/hip_bf16.h>
#include <math.h>

#define B_   2
#define N_   8192
#define D_   256
#define C_   6
#define HF_  64
#define WF_  64
#define P_   4
#define BN_  (B_ * N_)   // 16384

typedef __attribute__((ext_vector_type(8))) short short8v;   // 8 bf16 (4 VGPRs)
typedef __attribute__((ext_vector_type(4))) float floatx4;

typedef unsigned short ushort_t;

struct ushort4_t { ushort_t x, y, z, w; };

__device__ __forceinline__ float wred64(float v) {
#pragma unroll
  for (int o = 32; o > 0; o >>= 1) v += __shfl_xor(v, o, 64);
  return v;
}

__device__ __forceinline__ ushort_t f2b(float x) {
  union { float f; unsigned u; } c;
  c.f = x;
  unsigned r = c.u + 0x7FFFu + ((c.u >> 16) & 1u);
  return (ushort_t)(r >> 16);
}

__device__ __forceinline__ float b2f(ushort_t u) {
  union { unsigned u; float f; } c;
  c.u = ((unsigned)u) << 16;
  return c.f;
}

// ---------------------------------------------------------------------------
// Precompute (bf16, TRANSPOSED [n][k] layouts for GEMM B-operands):
//   At[j][i]  = A[i][j]  = sum_o Wq[o][i] Wk[o][j]
//   W2t[d][e] = B2[d][e] = sum_m Wo[d][m] Wv[m][e]
// ---------------------------------------------------------------------------
__global__ __launch_bounds__(256) void k_prec_mats(
    const float* __restrict__ Wq, const float* __restrict__ Wk,
    const float* __restrict__ Wv, const float* __restrict__ Wo,
    ushort_t* __restrict__ At, ushort_t* __restrict__ W2t) {
  const int i = threadIdx.x;
  const int blk = blockIdx.x;
  if (blk < 256) {
    const int j = blk;
    float acc = 0.f;
    for (int m = 0; m < 256; ++m) acc += Wq[m * 256 + i] * Wk[m * 256 + j];
    At[j * 256 + i] = f2b(acc);
  } else {
    const int d = blk - 256;
    float acc = 0.f;
    for (int m = 0; m < 256; ++m) acc += Wo[d * 256 + m] * Wv[m * 256 + i];
    W2t[d * 256 + i] = f2b(acc);
  }
}

// vec1 = Wk^T bq ; vec2 = Wq^T bk ; beta = Wo bv ; bqbk = bq.bk
__global__ __launch_bounds__(256) void k_prec_vecs(
    const float* __restrict__ Wq, const float* __restrict__ bk,
    const float* __restrict__ Wk, const float* __restrict__ bq,
    const float* __restrict__ Wo, const float* __restrict__ bv,
    float* __restrict__ vec1, float* __restrict__ vec2,
    float* __restrict__ beta, float* __restrict__ bqbk) {
  const int i = threadIdx.x;
  float a2 = 0.f, a1 = 0.f, ab = 0.f;
  for (int m = 0; m < 256; ++m) {
    a2 += Wq[m * 256 + i] * bk[m];
    a1 += Wk[m * 256 + i] * bq[m];
    ab += Wo[i * 256 + m] * bv[m];
  }
  vec2[i] = a2;
  vec1[i] = a1;
  beta[i] = ab;
  if (i == 0) {
    float s = 0.f;
    for (int m = 0; m < 256; ++m) s += bq[m] * bk[m];
    *bqbk = s;
  }
}

// ---------------------------------------------------------------------------
// LayerNorm -> QN (bf16) + offsets + gamma
// ---------------------------------------------------------------------------
__global__ __launch_bounds__(256) void k_ln(
    const float* __restrict__ Q, const float* __restrict__ ln_g,
    const float* __restrict__ ln_b, const float* __restrict__ Woff,
    const float* __restrict__ boff, const float* __restrict__ vec2,
    const float* __restrict__ bqbk, ushort_t* __restrict__ QNb,
    float* __restrict__ OFFS, float* __restrict__ GAM) {
  const int wave = threadIdx.x >> 6, lane = threadIdx.x & 63;
  const int m = blockIdx.x * 4 + wave;
  const int base = m * 256 + lane * 4;
  const float4 x = *(const float4*)&Q[base];
  float s = x.x + x.y + x.z + x.w;
  float sq = x.x * x.x + x.y * x.y + x.z * x.z + x.w * x.w;
  s = wred64(s);
  sq = wred64(sq);
  const float mu = s * (1.0f / 256.0f);
  const float var = sq * (1.0f / 256.0f) - mu * mu;
  const float rs = rsqrtf(var + 1e-5f);
  const float4 g = *(const float4*)&ln_g[lane * 4];
  const float4 bb = *(const float4*)&ln_b[lane * 4];
  float4 y;
  y.x = (x.x - mu) * rs * g.x + bb.x;
  y.y = (x.y - mu) * rs * g.y + bb.y;
  y.z = (x.z - mu) * rs * g.z + bb.z;
  y.w = (x.w - mu) * rs * g.w + bb.w;
  ushort4_t qo;
  qo.x = f2b(y.x); qo.y = f2b(y.y); qo.z = f2b(y.z); qo.w = f2b(y.w);
  *(ushort4_t*)&QNb[base] = qo;
  const float4 v2 = *(const float4*)&vec2[lane * 4];
  float gp = wred64(v2.x * y.x + v2.y * y.y + v2.z * y.z + v2.w * y.w);
  if (lane == 0) GAM[m] = gp + bqbk[0];
#pragma unroll
  for (int p2 = 0; p2 < 8; ++p2) {
    const float4 w = *(const float4*)&Woff[p2 * 256 + lane * 4];
    const float o = wred64(w.x * y.x + w.y * y.y + w.z * y.z + w.w * y.w);
    if (lane == 0) OFFS[m * 8 + p2] = (o + boff[p2]) * 0.05f;
  }
}

// ---------------------------------------------------------------------------
// Feature f32 -> bf16 conversion
// ---------------------------------------------------------------------------
__global__ __launch_bounds__(256) void k_cvt_feats(
    const float* __restrict__ f, ushort_t* __restrict__ fb) {
  const int idx = (blockIdx.x * 256 + threadIdx.x) * 4;
  const float4 v = *(const float4*)&f[idx];
  ushort4_t o;
  o.x = f2b(v.x); o.y = f2b(v.y); o.z = f2b(v.z); o.w = f2b(v.w);
  *(ushort4_t*)&fb[idx] = o;
}

// ---------------------------------------------------------------------------
// bf16 MFMA GEMM: Y[16384 x 256] = Xb[16384 x 256] @ Wt^T  (Wt is [n][k])
// BM=BN=128, BK=32, 256 threads = 4 waves (2x2), each wave 64x64 (4x4 frags).
// MODE 0: Y = bf16(acc + vec1[col])            (T)
// MODE 1: Y = f32(acc + resid + wsc[row]*beta[col] + bo[col])  (final out)
// ---------------------------------------------------------------------------
template <int MODE>
__global__ __launch_bounds__(256) void k_gemm(
    const ushort_t* __restrict__ Xb, const ushort_t* __restrict__ Wt,
    void* __restrict__ Yout, const float* __restrict__ vec1,
    const float* __restrict__ resid, const float* __restrict__ wsc,
    const float* __restrict__ beta, const float* __restrict__ bo) {
  __shared__ ushort_t As[128 * 40];  // rows padded 32->40 (80B stride)
  __shared__ ushort_t Bs[128 * 40];
  const int t = threadIdx.x;
  const int mb = blockIdx.x >> 1, nb = blockIdx.x & 1;
  const int m0 = mb * 128, n0 = nb * 128;
  const int wid = t >> 6, lane = t & 63;
  const int wm = wid >> 1, wn = wid & 1;
  const int lr = lane & 15, lh = lane >> 4;  // lh in 0..3

  floatx4 acc[4][4];
#pragma unroll
  for (int i = 0; i < 4; ++i)
#pragma unroll
    for (int j = 0; j < 4; ++j) acc[i][j] = (floatx4){0.f, 0.f, 0.f, 0.f};

  const int srow = t >> 1, shalf = t & 1;
  for (int k0 = 0; k0 < 256; k0 += 32) {
    // stage A (128x32) and B (128x32) with padded rows
    {
      const float4* ga = (const float4*)(Xb + (size_t)(m0 + srow) * 256 + k0 + shalf * 16);
      const float4 a0 = ga[0], a1 = ga[1];
      float4* la = (float4*)&As[srow * 40 + shalf * 16];
      la[0] = a0; la[1] = a1;
      const float4* gb = (const float4*)(Wt + (size_t)(n0 + srow) * 256 + k0 + shalf * 16);
      const float4 b0 = gb[0], b1 = gb[1];
      float4* lb = (float4*)&Bs[srow * 40 + shalf * 16];
      lb[0] = b0; lb[1] = b1;
    }
    __syncthreads();
    short8v a[4], b[4];
#pragma unroll
    for (int mi = 0; mi < 4; ++mi)
      a[mi] = *(const short8v*)&As[(wm * 64 + mi * 16 + lr) * 40 + lh * 8];
#pragma unroll
    for (int ni = 0; ni < 4; ++ni)
      b[ni] = *(const short8v*)&Bs[(wn * 64 + ni * 16 + lr) * 40 + lh * 8];
#pragma unroll
    for (int mi = 0; mi < 4; ++mi)
#pragma unroll
      for (int ni = 0; ni < 4; ++ni)
        acc[mi][ni] = __builtin_amdgcn_mfma_f32_16x16x32_bf16(
            a[mi], b[ni], acc[mi][ni], 0, 0, 0);
    __syncthreads();
  }

  // epilogue: D element (r): row = base + lh*4 + r, col = base + lr
#pragma unroll
  for (int mi = 0; mi < 4; ++mi) {
#pragma unroll
    for (int ni = 0; ni < 4; ++ni) {
      const int row0 = m0 + wm * 64 + mi * 16 + lh * 4;
      const int col = n0 + wn * 64 + ni * 16 + lr;
      if (MODE == 0) {
        ushort_t* Y = (ushort_t*)Yout;
        const float vc = vec1[col];
#pragma unroll
        for (int r = 0; r < 4; ++r)
          Y[(size_t)(row0 + r) * 256 + col] = f2b(acc[mi][ni][r] + vc);
      } else {
        float* Y = (float*)Yout;
        const float bt = beta[col], bb = bo[col];
#pragma unroll
        for (int r = 0; r < 4; ++r) {
          const int row = row0 + r;
          Y[(size_t)row * 256 + col] = acc[mi][ni][r] +
              resid[(size_t)row * 256 + col] + wsc[row] * bt + bb;
        }
      }
    }
  }
}

// ---------------------------------------------------------------------------
// Fused bilinear sampling + scores + weighted aggregation (templated on
// feature dtype). Fast path when all 4 sample points coincide.
// ---------------------------------------------------------------------------
template <typename FT>
__global__ __launch_bounds__(256) void k_sample(
    const FT* __restrict__ feats, const float* __restrict__ pix,
    const int* __restrict__ vmask, const ushort_t* __restrict__ Tb,
    const float* __restrict__ GAM, const float* __restrict__ OFFS,
    ushort_t* __restrict__ SVb, float* __restrict__ wscale) {
  const int wave = threadIdx.x >> 6, lane = threadIdx.x & 63;
  const int m = blockIdx.x * 4 + wave;
  const int b = m >> 13, n = m & 8191;
  const ushort4_t tu = *(const ushort4_t*)&Tb[m * 256 + lane * 4];
  const float t0 = b2f(tu.x), t1 = b2f(tu.y), t2 = b2f(tu.z), t3 = b2f(tu.w);
  const float gam = GAM[m];
  float offv[8];
#pragma unroll
  for (int p2 = 0; p2 < 8; ++p2) offv[p2] = OFFS[m * 8 + p2];
  const bool same = (offv[0] == offv[2]) && (offv[0] == offv[4]) &&
                    (offv[0] == offv[6]) && (offv[1] == offv[3]) &&
                    (offv[1] == offv[5]) && (offv[1] == offv[7]);
  float4 sv = {0.f, 0.f, 0.f, 0.f};
  float wsum = 0.f;
  int vcnt = 0;
  for (int c = 0; c < 6; ++c) {
    const int idx = (b * 6 + c) * 8192 + n;
    if (vmask[idx] == 0) continue;
    ++vcnt;
    const float pcx = pix[idx * 2 + 0];
    const float pcy = pix[idx * 2 + 1];
    const FT* fb = feats + (size_t)(b * 6 + c) * (HF_ * WF_ * 256);
    float4 sm = {0.f, 0.f, 0.f, 0.f};

    auto samplePoint = [&](float gx, float gy) {
      const float fx = (gx + 1.f) * 0.5f * 63.f;
      const float fy = (gy + 1.f) * 0.5f * 63.f;
      const float x0 = floorf(fx), y0 = floorf(fy);
      const float wx1 = fx - x0, wx0 = 1.f - wx1;
      const float wy1 = fy - y0, wy0 = 1.f - wy1;
#pragma unroll
      for (int cy = 0; cy < 2; ++cy) {
        const float yy = y0 + (float)cy;
        const float wy = cy ? wy1 : wy0;
        if (yy < 0.f || yy > 63.f || wy == 0.f) continue;
#pragma unroll
        for (int cx = 0; cx < 2; ++cx) {
          const float xx = x0 + (float)cx;
          const float wc = wy * (cx ? wx1 : wx0);
          if (xx < 0.f || xx > 63.f || wc == 0.f) continue;
          const int ri = (int)yy * WF_ + (int)xx;
          if constexpr (sizeof(FT) == 2) {
            const ushort4_t f4 = *(const ushort4_t*)&fb[(size_t)ri * 256 + lane * 4];
            sm.x += wc * b2f(f4.x);
            sm.y += wc * b2f(f4.y);
            sm.z += wc * b2f(f4.z);
            sm.w += wc * b2f(f4.w);
          } else {
            const float4 f4 = *(const float4*)&fb[(size_t)ri * 256 + lane * 4];
            sm.x += wc * f4.x;
            sm.y += wc * f4.y;
            sm.z += wc * f4.z;
            sm.w += wc * f4.w;
          }
        }
      }
    };

    if (same) {
      samplePoint(pcx + offv[0], pcy + offv[1]);
    } else {
#pragma unroll
      for (int p = 0; p < 4; ++p)
        samplePoint(pcx + offv[2 * p], pcy + offv[2 * p + 1]);
      sm.x *= 0.25f; sm.y *= 0.25f; sm.z *= 0.25f; sm.w *= 0.25f;
    }

    const float sc =
        wred64(t0 * sm.x + t1 * sm.y + t2 * sm.z + t3 * sm.w) + gam;
    const float w = sc * (1.f / 16.f);
    sv.x += w * sm.x;
    sv.y += w * sm.y;
    sv.z += w * sm.z;
    sv.w += w * sm.w;
    wsum += w;
  }
  const float tw = fmaxf((float)vcnt, 1.f);
  const float inv = 1.f / tw;
  ushort4_t o;
  o.x = f2b(sv.x * inv); o.y = f2b(sv.y * inv);
  o.z = f2b(sv.z * inv); o.w = f2b(sv.w * inv);
  *(ushort4_t*)&SVb[m * 256 + lane * 4] = o;
  if (lane == 0) wscale[m] = wsum * inv;
}

// ---------------------------------------------------------------------------
extern "C" void kernel_launch(void* const* d_in, const int* in_sizes, int n_in,
                              void* d_out, int out_size, void* d_ws,
                              size_t ws_size, hipStream_t stream) {
  const float* queries = (const float*)d_in[0];
  const float* feats = (const float*)d_in[1];
  const float* pix = (const float*)d_in[2];
  const int* vmask = (const int*)d_in[3];
  const float* Wq = (const float*)d_in[4];
  const float* bq = (const float*)d_in[5];
  const float* Wk = (const float*)d_in[6];
  const float* bk = (const float*)d_in[7];
  const float* Wv = (const float*)d_in[8];
  const float* bv = (const float*)d_in[9];
  const float* Wo = (const float*)d_in[10];
  const float* bo = (const float*)d_in[11];
  const float* Woff = (const float*)d_in[12];
  const float* boff = (const float*)d_in[13];
  const float* ln_g = (const float*)d_in[14];
  const float* ln_b = (const float*)d_in[15];

  char* w = (char*)d_ws;
  ushort_t* At = (ushort_t*)w;   w += 256 * 256 * 2;
  ushort_t* W2t = (ushort_t*)w;  w += 256 * 256 * 2;
  float* vec1 = (float*)w;       w += 1024;
  float* vec2 = (float*)w;       w += 1024;
  float* beta = (float*)w;       w += 1024;
  float* bqbk = (float*)w;       w += 256;
  float* OFFS = (float*)w;       w += (size_t)BN_ * 8 * 4;
  float* GAM = (float*)w;        w += (size_t)BN_ * 4;
  float* WSC = (float*)w;        w += (size_t)BN_ * 4;
  ushort_t* QNb = (ushort_t*)w;  w += (size_t)BN_ * 256 * 2;  // SVb overlays
  ushort_t* SVb = QNb;
  ushort_t* featb = (ushort_t*)w;
  const size_t featElems = (size_t)B_ * C_ * HF_ * WF_ * 256;  // 12,582,912
  const size_t need = (size_t)(w - (char*)d_ws) + featElems * 2;
  const bool useBf16Feat = (ws_size >= need);

  ushort_t* Tb = (ushort_t*)d_out;  // bf16 T lives in d_out until final GEMM
  float* out = (float*)d_out;

  k_prec_mats<<<512, 256, 0, stream>>>(Wq, Wk, Wv, Wo, At, W2t);
  k_prec_vecs<<<1, 256, 0, stream>>>(Wq, bk, Wk, bq, Wo, bv, vec1, vec2, beta,
                                     bqbk);
  k_ln<<<BN_ / 4, 256, 0, stream>>>(queries, ln_g, ln_b, Woff, boff, vec2, bqbk,
                                    QNb, OFFS, GAM);
  if (useBf16Feat)
    k_cvt_feats<<<(int)(featElems / 1024), 256, 0, stream>>>(feats, featb);
  k_gemm<0><<<256, 256, 0, stream>>>(QNb, At, (void*)Tb, vec1, nullptr,
                                     nullptr, nullptr, nullptr);
  if (useBf16Feat)
    k_sample<ushort_t><<<BN_ / 4, 256, 0, stream>>>(featb, pix, vmask, Tb, GAM,
                                                    OFFS, SVb, WSC);
  else
    k_sample<float><<<BN_ / 4, 256, 0, stream>>>(feats, pix, vmask, Tb, GAM,
                                                 OFFS, SVb, WSC);
  k_gemm<1><<<256, 256, 0, stream>>>(SVb, W2t, (void*)out, nullptr, queries,
                                     WSC, beta, bo);
}

// Round 3
// 134.823 us; speedup vs baseline: 1.5092x; 1.0054x over previous
//
#include <hip/hip_runtime.h>
#include <hip/hip_bf16.h>
#include <math.h>

#define B_   2
#define N_   8192
#define D_   256
#define C_   6
#define HF_  64
#define WF_  64
#define P_   4
#define BN_  (B_ * N_)   // 16384

typedef __attribute__((ext_vector_type(8))) short short8v;   // 8 bf16 (4 VGPRs)
typedef __attribute__((ext_vector_type(4))) float floatx4;

typedef unsigned short ushort_t;

struct ushort4_t { ushort_t x, y, z, w; };

__device__ __forceinline__ float wred64(float v) {
#pragma unroll
  for (int o = 32; o > 0; o >>= 1) v += __shfl_xor(v, o, 64);
  return v;
}

__device__ __forceinline__ ushort_t f2b(float x) {
  union { float f; unsigned u; } c;
  c.f = x;
  unsigned r = c.u + 0x7FFFu + ((c.u >> 16) & 1u);
  return (ushort_t)(r >> 16);
}

__device__ __forceinline__ float b2f(ushort_t u) {
  union { unsigned u; float f; } c;
  c.u = ((unsigned)u) << 16;
  return c.f;
}

// ---------------------------------------------------------------------------
// Combined precompute: blocks 0..255 -> At (A^T), 256..511 -> W2t, 512 -> vecs
//   At[j][i]  = sum_o Wq[o][i] Wk[o][j]        (bf16, [n][k] for GEMM0 B-op)
//   W2t[d][e] = sum_m Wo[d][m] Wv[m][e]        (bf16, [n][k] for GEMM1 B-op)
//   vec1 = Wk^T bq ; vec2 = Wq^T bk ; beta = Wo bv ; bqbk = bq.bk
// ---------------------------------------------------------------------------
__global__ __launch_bounds__(256) void k_prec(
    const float* __restrict__ Wq, const float* __restrict__ Wk,
    const float* __restrict__ Wv, const float* __restrict__ Wo,
    const float* __restrict__ bq, const float* __restrict__ bk,
    const float* __restrict__ bv,
    ushort_t* __restrict__ At, ushort_t* __restrict__ W2t,
    float* __restrict__ vec1, float* __restrict__ vec2,
    float* __restrict__ beta, float* __restrict__ bqbk) {
  const int i = threadIdx.x;
  const int blk = blockIdx.x;
  if (blk < 256) {
    const int j = blk;
    float acc = 0.f;
    for (int m = 0; m < 256; ++m) acc += Wq[m * 256 + i] * Wk[m * 256 + j];
    At[j * 256 + i] = f2b(acc);
  } else if (blk < 512) {
    const int d = blk - 256;
    float acc = 0.f;
    for (int m = 0; m < 256; ++m) acc += Wo[d * 256 + m] * Wv[m * 256 + i];
    W2t[d * 256 + i] = f2b(acc);
  } else {
    float a2 = 0.f, a1 = 0.f, ab = 0.f;
    for (int m = 0; m < 256; ++m) {
      a2 += Wq[m * 256 + i] * bk[m];
      a1 += Wk[m * 256 + i] * bq[m];
      ab += Wo[i * 256 + m] * bv[m];
    }
    vec2[i] = a2;
    vec1[i] = a1;
    beta[i] = ab;
    if (i == 0) {
      float s = 0.f;
      for (int m = 0; m < 256; ++m) s += bq[m] * bk[m];
      *bqbk = s;
    }
  }
}

// ---------------------------------------------------------------------------
// LayerNorm -> QN (bf16) + offsets + gamma
// ---------------------------------------------------------------------------
__global__ __launch_bounds__(256) void k_ln(
    const float* __restrict__ Q, const float* __restrict__ ln_g,
    const float* __restrict__ ln_b, const float* __restrict__ Woff,
    const float* __restrict__ boff, const float* __restrict__ vec2,
    const float* __restrict__ bqbk, ushort_t* __restrict__ QNb,
    float* __restrict__ OFFS, float* __restrict__ GAM) {
  const int wave = threadIdx.x >> 6, lane = threadIdx.x & 63;
  const int m = blockIdx.x * 4 + wave;
  const int base = m * 256 + lane * 4;
  const float4 x = *(const float4*)&Q[base];
  float s = x.x + x.y + x.z + x.w;
  float sq = x.x * x.x + x.y * x.y + x.z * x.z + x.w * x.w;
  s = wred64(s);
  sq = wred64(sq);
  const float mu = s * (1.0f / 256.0f);
  const float var = sq * (1.0f / 256.0f) - mu * mu;
  const float rs = rsqrtf(var + 1e-5f);
  const float4 g = *(const float4*)&ln_g[lane * 4];
  const float4 bb = *(const float4*)&ln_b[lane * 4];
  float4 y;
  y.x = (x.x - mu) * rs * g.x + bb.x;
  y.y = (x.y - mu) * rs * g.y + bb.y;
  y.z = (x.z - mu) * rs * g.z + bb.z;
  y.w = (x.w - mu) * rs * g.w + bb.w;
  ushort4_t qo;
  qo.x = f2b(y.x); qo.y = f2b(y.y); qo.z = f2b(y.z); qo.w = f2b(y.w);
  *(ushort4_t*)&QNb[base] = qo;
  const float4 v2 = *(const float4*)&vec2[lane * 4];
  float gp = wred64(v2.x * y.x + v2.y * y.y + v2.z * y.z + v2.w * y.w);
  if (lane == 0) GAM[m] = gp + bqbk[0];
#pragma unroll
  for (int p2 = 0; p2 < 8; ++p2) {
    const float4 w = *(const float4*)&Woff[p2 * 256 + lane * 4];
    const float o = wred64(w.x * y.x + w.y * y.y + w.z * y.z + w.w * y.w);
    if (lane == 0) OFFS[m * 8 + p2] = (o + boff[p2]) * 0.05f;
  }
}

// ---------------------------------------------------------------------------
// Feature f32 -> bf16 conversion
// ---------------------------------------------------------------------------
__global__ __launch_bounds__(256) void k_cvt_feats(
    const float* __restrict__ f, ushort_t* __restrict__ fb) {
  const int idx = (blockIdx.x * 256 + threadIdx.x) * 4;
  const float4 v = *(const float4*)&f[idx];
  ushort4_t o;
  o.x = f2b(v.x); o.y = f2b(v.y); o.z = f2b(v.z); o.w = f2b(v.w);
  *(ushort4_t*)&fb[idx] = o;
}

// ---------------------------------------------------------------------------
// bf16 MFMA GEMM: Y[16384 x 256] = Xb[16384 x 256] @ Wt^T  (Wt is [n][k])
// BM=BN=128, BK=64, 256 threads = 4 waves (2x2), each wave 64x64 (4x4 frags).
// Epilogue: per-wave 16x16 LDS transpose -> vectorized stores.
// MODE 0: Y = bf16(acc + vec1[col])
// MODE 1: Y = f32(acc + resid + wsc[row]*beta[col] + bo[col])
// ---------------------------------------------------------------------------
template <int MODE>
__global__ __launch_bounds__(256) void k_gemm(
    const ushort_t* __restrict__ Xb, const ushort_t* __restrict__ Wt,
    void* __restrict__ Yout, const float* __restrict__ vec1,
    const float* __restrict__ resid, const float* __restrict__ wsc,
    const float* __restrict__ beta, const float* __restrict__ bo) {
  __shared__ ushort_t As[128 * 68];  // rows padded 64->68 shorts (136B)
  __shared__ ushort_t Bs[128 * 68];
  __shared__ float tr[4][16 * 17];   // per-wave transpose buffer
  const int t = threadIdx.x;
  const int mb = blockIdx.x >> 1, nb = blockIdx.x & 1;
  const int m0 = mb * 128, n0 = nb * 128;
  const int wid = t >> 6, lane = t & 63;
  const int wm = wid >> 1, wn = wid & 1;
  const int lr = lane & 15, lh = lane >> 4;  // lh in 0..3

  floatx4 acc[4][4];
#pragma unroll
  for (int i = 0; i < 4; ++i)
#pragma unroll
    for (int j = 0; j < 4; ++j) acc[i][j] = (floatx4){0.f, 0.f, 0.f, 0.f};

  for (int k0 = 0; k0 < 256; k0 += 64) {
    // stage A (128x64) and B (128x64); 4 x 16B segments per thread each
#pragma unroll
    for (int q = 0; q < 4; ++q) {
      const int s = t * 4 + q;
      const int row = s >> 3;
      const int off = (s & 7) * 8;  // shorts
      *(float4*)&As[row * 68 + off] =
          *(const float4*)(Xb + (size_t)(m0 + row) * 256 + k0 + off);
      *(float4*)&Bs[row * 68 + off] =
          *(const float4*)(Wt + (size_t)(n0 + row) * 256 + k0 + off);
    }
    __syncthreads();
#pragma unroll
    for (int kk = 0; kk < 64; kk += 32) {
      short8v a[4], b[4];
#pragma unroll
      for (int mi = 0; mi < 4; ++mi)
        a[mi] = *(const short8v*)&As[(wm * 64 + mi * 16 + lr) * 68 + kk + lh * 8];
#pragma unroll
      for (int ni = 0; ni < 4; ++ni)
        b[ni] = *(const short8v*)&Bs[(wn * 64 + ni * 16 + lr) * 68 + kk + lh * 8];
#pragma unroll
      for (int mi = 0; mi < 4; ++mi)
#pragma unroll
        for (int ni = 0; ni < 4; ++ni)
          acc[mi][ni] = __builtin_amdgcn_mfma_f32_16x16x32_bf16(
              a[mi], b[ni], acc[mi][ni], 0, 0, 0);
    }
    __syncthreads();
  }

  // epilogue: per-frag 16x16 transpose through per-wave LDS buffer.
  // acc elem r of frag (mi,ni): row = mi*16 + lh*4 + r, col = ni*16 + lr.
  // After transpose lane holds cols lh*4..+3 of row lr -> vectorized store.
  float* tb = tr[wid];
#pragma unroll
  for (int mi = 0; mi < 4; ++mi) {
#pragma unroll
    for (int ni = 0; ni < 4; ++ni) {
#pragma unroll
      for (int r = 0; r < 4; ++r)
        tb[(lh * 4 + r) * 17 + lr] = acc[mi][ni][r];
      // per-wave LDS ops are in-order; compiler inserts lgkmcnt before use
      const float4 v = *(const float4*)&tb[lr * 17 + lh * 4];
      const int row = m0 + wm * 64 + mi * 16 + lr;
      const int col = n0 + wn * 64 + ni * 16 + lh * 4;
      if (MODE == 0) {
        const float4 vc = *(const float4*)&vec1[col];
        ushort4_t o;
        o.x = f2b(v.x + vc.x);
        o.y = f2b(v.y + vc.y);
        o.z = f2b(v.z + vc.z);
        o.w = f2b(v.w + vc.w);
        *(ushort4_t*)((ushort_t*)Yout + (size_t)row * 256 + col) = o;
      } else {
        const float4 rv = *(const float4*)&resid[(size_t)row * 256 + col];
        const float4 bt = *(const float4*)&beta[col];
        const float4 bv4 = *(const float4*)&bo[col];
        const float wscale = wsc[row];
        float4 o;
        o.x = v.x + rv.x + wscale * bt.x + bv4.x;
        o.y = v.y + rv.y + wscale * bt.y + bv4.y;
        o.z = v.z + rv.z + wscale * bt.z + bv4.z;
        o.w = v.w + rv.w + wscale * bt.w + bv4.w;
        *(float4*)((float*)Yout + (size_t)row * 256 + col) = o;
      }
    }
  }
}

// ---------------------------------------------------------------------------
// Fused bilinear sampling + scores + weighted aggregation.
// One BLOCK per query (384 threads = 6 waves), wave c handles camera c.
// LDS reduce across cameras.
// ---------------------------------------------------------------------------
__global__ __launch_bounds__(384) void k_sample(
    const ushort_t* __restrict__ feats, const float* __restrict__ pix,
    const int* __restrict__ vmask, const ushort_t* __restrict__ Tb,
    const float* __restrict__ GAM, const float* __restrict__ OFFS,
    ushort_t* __restrict__ SVb, float* __restrict__ wscale) {
  __shared__ float sm_s[6 * 256];
  __shared__ float w_s[6];
  __shared__ int v_s[6];
  const int c = threadIdx.x >> 6, lane = threadIdx.x & 63;
  const int m = blockIdx.x;
  const int b = m >> 13, n = m & 8191;
  const int idx = (b * 6 + c) * 8192 + n;
  const int valid = vmask[idx];
  float4 wsm = {0.f, 0.f, 0.f, 0.f};
  float w = 0.f;
  if (valid) {
    const ushort4_t tu = *(const ushort4_t*)&Tb[m * 256 + lane * 4];
    const float t0 = b2f(tu.x), t1 = b2f(tu.y), t2 = b2f(tu.z), t3 = b2f(tu.w);
    float offv[8];
#pragma unroll
    for (int p2 = 0; p2 < 8; ++p2) offv[p2] = OFFS[m * 8 + p2];
    const bool same = (offv[0] == offv[2]) && (offv[0] == offv[4]) &&
                      (offv[0] == offv[6]) && (offv[1] == offv[3]) &&
                      (offv[1] == offv[5]) && (offv[1] == offv[7]);
    const float pcx = pix[idx * 2 + 0];
    const float pcy = pix[idx * 2 + 1];
    const ushort_t* fb = feats + (size_t)(b * 6 + c) * (HF_ * WF_ * 256);
    float4 sm = {0.f, 0.f, 0.f, 0.f};

    auto samplePoint = [&](float gx, float gy) {
      const float fx = (gx + 1.f) * 0.5f * 63.f;
      const float fy = (gy + 1.f) * 0.5f * 63.f;
      const float x0 = floorf(fx), y0 = floorf(fy);
      const float wx1 = fx - x0, wx0 = 1.f - wx1;
      const float wy1 = fy - y0, wy0 = 1.f - wy1;
#pragma unroll
      for (int cy = 0; cy < 2; ++cy) {
        const float yy = y0 + (float)cy;
        const float wy = cy ? wy1 : wy0;
        if (yy < 0.f || yy > 63.f || wy == 0.f) continue;
#pragma unroll
        for (int cx = 0; cx < 2; ++cx) {
          const float xx = x0 + (float)cx;
          const float wc = wy * (cx ? wx1 : wx0);
          if (xx < 0.f || xx > 63.f || wc == 0.f) continue;
          const int ri = (int)yy * WF_ + (int)xx;
          const ushort4_t f4 = *(const ushort4_t*)&fb[(size_t)ri * 256 + lane * 4];
          sm.x += wc * b2f(f4.x);
          sm.y += wc * b2f(f4.y);
          sm.z += wc * b2f(f4.z);
          sm.w += wc * b2f(f4.w);
        }
      }
    };

    if (same) {
      samplePoint(pcx + offv[0], pcy + offv[1]);
    } else {
#pragma unroll
      for (int p = 0; p < 4; ++p)
        samplePoint(pcx + offv[2 * p], pcy + offv[2 * p + 1]);
      sm.x *= 0.25f; sm.y *= 0.25f; sm.z *= 0.25f; sm.w *= 0.25f;
    }

    const float sc =
        wred64(t0 * sm.x + t1 * sm.y + t2 * sm.z + t3 * sm.w) + GAM[m];
    w = sc * (1.f / 16.f);
    wsm.x = w * sm.x;
    wsm.y = w * sm.y;
    wsm.z = w * sm.z;
    wsm.w = w * sm.w;
  }
  *(float4*)&sm_s[c * 256 + lane * 4] = wsm;
  if (lane == 0) {
    w_s[c] = w;
    v_s[c] = valid ? 1 : 0;
  }
  __syncthreads();
  if (threadIdx.x < 256) {
    const int ch = threadIdx.x;
    float s = 0.f;
#pragma unroll
    for (int cc = 0; cc < 6; ++cc) s += sm_s[cc * 256 + ch];
    float wsum = 0.f;
    int vcnt = 0;
#pragma unroll
    for (int cc = 0; cc < 6; ++cc) {
      wsum += w_s[cc];
      vcnt += v_s[cc];
    }
    const float inv = 1.f / fmaxf((float)vcnt, 1.f);
    SVb[(size_t)m * 256 + ch] = f2b(s * inv);
    if (ch == 0) wscale[m] = wsum * inv;
  }
}

// ---------------------------------------------------------------------------
extern "C" void kernel_launch(void* const* d_in, const int* in_sizes, int n_in,
                              void* d_out, int out_size, void* d_ws,
                              size_t ws_size, hipStream_t stream) {
  const float* queries = (const float*)d_in[0];
  const float* feats = (const float*)d_in[1];
  const float* pix = (const float*)d_in[2];
  const int* vmask = (const int*)d_in[3];
  const float* Wq = (const float*)d_in[4];
  const float* bq = (const float*)d_in[5];
  const float* Wk = (const float*)d_in[6];
  const float* bk = (const float*)d_in[7];
  const float* Wv = (const float*)d_in[8];
  const float* bv = (const float*)d_in[9];
  const float* Wo = (const float*)d_in[10];
  const float* bo = (const float*)d_in[11];
  const float* Woff = (const float*)d_in[12];
  const float* boff = (const float*)d_in[13];
  const float* ln_g = (const float*)d_in[14];
  const float* ln_b = (const float*)d_in[15];

  char* w = (char*)d_ws;
  ushort_t* At = (ushort_t*)w;   w += 256 * 256 * 2;
  ushort_t* W2t = (ushort_t*)w;  w += 256 * 256 * 2;
  float* vec1 = (float*)w;       w += 1024;
  float* vec2 = (float*)w;       w += 1024;
  float* beta = (float*)w;       w += 1024;
  float* bqbk = (float*)w;       w += 256;
  float* OFFS = (float*)w;       w += (size_t)BN_ * 8 * 4;
  float* GAM = (float*)w;        w += (size_t)BN_ * 4;
  float* WSC = (float*)w;        w += (size_t)BN_ * 4;
  ushort_t* QNb = (ushort_t*)w;  w += (size_t)BN_ * 256 * 2;  // SVb overlays
  ushort_t* SVb = QNb;
  ushort_t* featb = (ushort_t*)w;
  const size_t featElems = (size_t)B_ * C_ * HF_ * WF_ * 256;  // 12,582,912
  const size_t need = (size_t)(w - (char*)d_ws) + featElems * 2;
  const bool useBf16Feat = (ws_size >= need);

  ushort_t* Tb = (ushort_t*)d_out;  // bf16 T lives in d_out until final GEMM
  float* out = (float*)d_out;

  k_prec<<<513, 256, 0, stream>>>(Wq, Wk, Wv, Wo, bq, bk, bv, At, W2t, vec1,
                                  vec2, beta, bqbk);
  k_ln<<<BN_ / 4, 256, 0, stream>>>(queries, ln_g, ln_b, Woff, boff, vec2, bqbk,
                                    QNb, OFFS, GAM);
  if (useBf16Feat)
    k_cvt_feats<<<(int)(featElems / 1024), 256, 0, stream>>>(feats, featb);
  k_gemm<0><<<256, 256, 0, stream>>>(QNb, At, (void*)Tb, vec1, nullptr,
                                     nullptr, nullptr, nullptr);
  k_sample<<<BN_, 384, 0, stream>>>(useBf16Feat ? featb : (ushort_t*)nullptr,
                                    pix, vmask, Tb, GAM, OFFS, SVb, WSC);
  k_gemm<1><<<256, 256, 0, stream>>>(SVb, W2t, (void*)out, nullptr, queries,
                                     WSC, beta, bo);
}

// Round 4
// 101.237 us; speedup vs baseline: 2.0098x; 1.3318x over previous
//
#include <hip/hip_runtime.h>
#include <hip/hip_bf16.h>
#include <math.h>

#define B_   2
#define N_   8192
#define D_   256
#define C_   6
#define HF_  64
#define WF_  64
#define P_   4
#define BN_  (B_ * N_)   // 16384

typedef __attribute__((ext_vector_type(8))) short short8v;   // 8 bf16 (4 VGPRs)
typedef __attribute__((ext_vector_type(4))) float floatx4;

typedef unsigned short ushort_t;

struct ushort4_t { ushort_t x, y, z, w; };

__device__ __forceinline__ float wred64(float v) {
#pragma unroll
  for (int o = 32; o > 0; o >>= 1) v += __shfl_xor(v, o, 64);
  return v;
}

__device__ __forceinline__ ushort_t f2b(float x) {
  union { float f; unsigned u; } c;
  c.f = x;
  unsigned r = c.u + 0x7FFFu + ((c.u >> 16) & 1u);
  return (ushort_t)(r >> 16);
}

__device__ __forceinline__ float b2f(ushort_t u) {
  union { unsigned u; float f; } c;
  c.u = ((unsigned)u) << 16;
  return c.f;
}

// ---------------------------------------------------------------------------
// K1: merged pre-pass. Blocks [0,cvtBlocks): feature f32->bf16 cvt.
// [cvtBlocks, cvtBlocks+513): weight precompute (At, W2t, vecs).
// [cvtBlocks+513, +4096): LayerNorm -> QNb + OFFS.
// No inter-block dependencies (gamma moved to k_sample).
// ---------------------------------------------------------------------------
__global__ __launch_bounds__(256) void k_pre(
    const float* __restrict__ feats, ushort_t* __restrict__ featb,
    const float* __restrict__ Wq, const float* __restrict__ Wk,
    const float* __restrict__ Wv, const float* __restrict__ Wo,
    const float* __restrict__ bq, const float* __restrict__ bk,
    const float* __restrict__ bv,
    ushort_t* __restrict__ At, ushort_t* __restrict__ W2t,
    float* __restrict__ vec1, float* __restrict__ vec2,
    float* __restrict__ beta, float* __restrict__ bqbk,
    const float* __restrict__ Q, const float* __restrict__ ln_g,
    const float* __restrict__ ln_b, const float* __restrict__ Woff,
    const float* __restrict__ boff, ushort_t* __restrict__ QNb,
    float* __restrict__ OFFS, int cvtBlocks) {
  const int blk = blockIdx.x;
  const int t = threadIdx.x;
  if (blk < cvtBlocks) {
    // ---- feature conversion: 1024 elems per block
    const int idx = (blk * 256 + t) * 4;
    const float4 v = *(const float4*)&feats[idx];
    ushort4_t o;
    o.x = f2b(v.x); o.y = f2b(v.y); o.z = f2b(v.z); o.w = f2b(v.w);
    *(ushort4_t*)&featb[idx] = o;
    return;
  }
  const int bi = blk - cvtBlocks;
  if (bi < 513) {
    const int i = t;
    if (bi < 256) {
      const int j = bi;
      float acc = 0.f;
      for (int m = 0; m < 256; ++m) acc += Wq[m * 256 + i] * Wk[m * 256 + j];
      At[j * 256 + i] = f2b(acc);
    } else if (bi < 512) {
      const int d = bi - 256;
      float acc = 0.f;
      for (int m = 0; m < 256; ++m) acc += Wo[d * 256 + m] * Wv[m * 256 + i];
      W2t[d * 256 + i] = f2b(acc);
    } else {
      float a2 = 0.f, a1 = 0.f, ab = 0.f;
      for (int m = 0; m < 256; ++m) {
        a2 += Wq[m * 256 + i] * bk[m];
        a1 += Wk[m * 256 + i] * bq[m];
        ab += Wo[i * 256 + m] * bv[m];
      }
      vec2[i] = a2;
      vec1[i] = a1;
      beta[i] = ab;
      if (i == 0) {
        float s = 0.f;
        for (int m = 0; m < 256; ++m) s += bq[m] * bk[m];
        *bqbk = s;
      }
    }
    return;
  }
  // ---- LayerNorm + offsets
  const int lb = bi - 513;
  const int wave = t >> 6, lane = t & 63;
  const int m = lb * 4 + wave;
  const int base = m * 256 + lane * 4;
  const float4 x = *(const float4*)&Q[base];
  float s = x.x + x.y + x.z + x.w;
  float sq = x.x * x.x + x.y * x.y + x.z * x.z + x.w * x.w;
  s = wred64(s);
  sq = wred64(sq);
  const float mu = s * (1.0f / 256.0f);
  const float var = sq * (1.0f / 256.0f) - mu * mu;
  const float rs = rsqrtf(var + 1e-5f);
  const float4 g = *(const float4*)&ln_g[lane * 4];
  const float4 bb = *(const float4*)&ln_b[lane * 4];
  float4 y;
  y.x = (x.x - mu) * rs * g.x + bb.x;
  y.y = (x.y - mu) * rs * g.y + bb.y;
  y.z = (x.z - mu) * rs * g.z + bb.z;
  y.w = (x.w - mu) * rs * g.w + bb.w;
  ushort4_t qo;
  qo.x = f2b(y.x); qo.y = f2b(y.y); qo.z = f2b(y.z); qo.w = f2b(y.w);
  *(ushort4_t*)&QNb[base] = qo;
#pragma unroll
  for (int p2 = 0; p2 < 8; ++p2) {
    const float4 w = *(const float4*)&Woff[p2 * 256 + lane * 4];
    const float o = wred64(w.x * y.x + w.y * y.y + w.z * y.z + w.w * y.w);
    if (lane == 0) OFFS[m * 8 + p2] = (o + boff[p2]) * 0.05f;
  }
}

// ---------------------------------------------------------------------------
// bf16 MFMA GEMM: Y[16384 x 256] = Xb[16384 x 256] @ Wt^T  (Wt is [n][k])
// BM=BN=128, BK=64, 256 threads = 4 waves (2x2), each wave 64x64 (4x4 frags).
// Epilogue: per-wave 16x16 LDS transpose -> vectorized stores.
// MODE 0: Y = bf16(acc + vec1[col])
// MODE 1: Y = f32(acc + resid + wsc[row]*beta[col] + bo[col])
// ---------------------------------------------------------------------------
template <int MODE>
__global__ __launch_bounds__(256) void k_gemm(
    const ushort_t* __restrict__ Xb, const ushort_t* __restrict__ Wt,
    void* __restrict__ Yout, const float* __restrict__ vec1,
    const float* __restrict__ resid, const float* __restrict__ wsc,
    const float* __restrict__ beta, const float* __restrict__ bo) {
  __shared__ ushort_t As[128 * 68];  // rows padded 64->68 shorts (136B)
  __shared__ ushort_t Bs[128 * 68];
  __shared__ float tr[4][16 * 17];   // per-wave transpose buffer
  const int t = threadIdx.x;
  const int mb = blockIdx.x >> 1, nb = blockIdx.x & 1;
  const int m0 = mb * 128, n0 = nb * 128;
  const int wid = t >> 6, lane = t & 63;
  const int wm = wid >> 1, wn = wid & 1;
  const int lr = lane & 15, lh = lane >> 4;  // lh in 0..3

  floatx4 acc[4][4];
#pragma unroll
  for (int i = 0; i < 4; ++i)
#pragma unroll
    for (int j = 0; j < 4; ++j) acc[i][j] = (floatx4){0.f, 0.f, 0.f, 0.f};

  for (int k0 = 0; k0 < 256; k0 += 64) {
#pragma unroll
    for (int q = 0; q < 4; ++q) {
      const int s = t * 4 + q;
      const int row = s >> 3;
      const int off = (s & 7) * 8;  // shorts
      *(float4*)&As[row * 68 + off] =
          *(const float4*)(Xb + (size_t)(m0 + row) * 256 + k0 + off);
      *(float4*)&Bs[row * 68 + off] =
          *(const float4*)(Wt + (size_t)(n0 + row) * 256 + k0 + off);
    }
    __syncthreads();
#pragma unroll
    for (int kk = 0; kk < 64; kk += 32) {
      short8v a[4], b[4];
#pragma unroll
      for (int mi = 0; mi < 4; ++mi)
        a[mi] = *(const short8v*)&As[(wm * 64 + mi * 16 + lr) * 68 + kk + lh * 8];
#pragma unroll
      for (int ni = 0; ni < 4; ++ni)
        b[ni] = *(const short8v*)&Bs[(wn * 64 + ni * 16 + lr) * 68 + kk + lh * 8];
#pragma unroll
      for (int mi = 0; mi < 4; ++mi)
#pragma unroll
        for (int ni = 0; ni < 4; ++ni)
          acc[mi][ni] = __builtin_amdgcn_mfma_f32_16x16x32_bf16(
              a[mi], b[ni], acc[mi][ni], 0, 0, 0);
    }
    __syncthreads();
  }

  float* tb = tr[wid];
#pragma unroll
  for (int mi = 0; mi < 4; ++mi) {
#pragma unroll
    for (int ni = 0; ni < 4; ++ni) {
#pragma unroll
      for (int r = 0; r < 4; ++r)
        tb[(lh * 4 + r) * 17 + lr] = acc[mi][ni][r];
      const float4 v = *(const float4*)&tb[lr * 17 + lh * 4];
      const int row = m0 + wm * 64 + mi * 16 + lr;
      const int col = n0 + wn * 64 + ni * 16 + lh * 4;
      if (MODE == 0) {
        const float4 vc = *(const float4*)&vec1[col];
        ushort4_t o;
        o.x = f2b(v.x + vc.x);
        o.y = f2b(v.y + vc.y);
        o.z = f2b(v.z + vc.z);
        o.w = f2b(v.w + vc.w);
        *(ushort4_t*)((ushort_t*)Yout + (size_t)row * 256 + col) = o;
      } else {
        const float4 rv = *(const float4*)&resid[(size_t)row * 256 + col];
        const float4 bt = *(const float4*)&beta[col];
        const float4 bv4 = *(const float4*)&bo[col];
        const float wscale = wsc[row];
        float4 o;
        o.x = v.x + rv.x + wscale * bt.x + bv4.x;
        o.y = v.y + rv.y + wscale * bt.y + bv4.y;
        o.z = v.z + rv.z + wscale * bt.z + bv4.z;
        o.w = v.w + rv.w + wscale * bt.w + bv4.w;
        *(float4*)((float*)Yout + (size_t)row * 256 + col) = o;
      }
    }
  }
}

// ---------------------------------------------------------------------------
// Fused sampling + scores + aggregation. Wave per query; all cameras kept
// in registers; gathers for all valid cameras issued before any reduction;
// 7 butterfly reductions (6 camera dots + gamma dot) interleaved.
// ---------------------------------------------------------------------------
template <typename FT>
__global__ __launch_bounds__(256) void k_sample(
    const FT* __restrict__ feats, const float* __restrict__ pix,
    const int* __restrict__ vmask, const ushort_t* __restrict__ Tb,
    const ushort_t* __restrict__ QNb, const float* __restrict__ vec2,
    const float* __restrict__ bqbk, const float* __restrict__ OFFS,
    ushort_t* __restrict__ SVb, float* __restrict__ wscale) {
  const int wave = threadIdx.x >> 6, lane = threadIdx.x & 63;
  const int m = blockIdx.x * 4 + wave;
  const int b = m >> 13, n = m & 8191;

  const ushort4_t tu = *(const ushort4_t*)&Tb[(size_t)m * 256 + lane * 4];
  const float t0 = b2f(tu.x), t1 = b2f(tu.y), t2 = b2f(tu.z), t3 = b2f(tu.w);
  const ushort4_t qu = *(const ushort4_t*)&QNb[(size_t)m * 256 + lane * 4];
  const float4 v2 = *(const float4*)&vec2[lane * 4];
  const float dpg0 = v2.x * b2f(qu.x) + v2.y * b2f(qu.y) +
                     v2.z * b2f(qu.z) + v2.w * b2f(qu.w);

  float offv[8];
#pragma unroll
  for (int p2 = 0; p2 < 8; ++p2) offv[p2] = OFFS[m * 8 + p2];
  const bool same = (offv[0] == offv[2]) && (offv[0] == offv[4]) &&
                    (offv[0] == offv[6]) && (offv[1] == offv[3]) &&
                    (offv[1] == offv[5]) && (offv[1] == offv[7]);

  int validc[6];
  float pcx[6], pcy[6];
#pragma unroll
  for (int c = 0; c < 6; ++c) {
    const int idx = (b * 6 + c) * 8192 + n;
    validc[c] = vmask[idx];
    pcx[c] = 0.f;
    pcy[c] = 0.f;
    if (validc[c]) {
      pcx[c] = pix[(size_t)idx * 2 + 0];
      pcy[c] = pix[(size_t)idx * 2 + 1];
    }
  }

  float4 smc[6];
#pragma unroll
  for (int c = 0; c < 6; ++c) {
    smc[c] = (float4){0.f, 0.f, 0.f, 0.f};
    if (!validc[c]) continue;
    const FT* fb = feats + (size_t)(b * 6 + c) * (HF_ * WF_ * 256);
    float4 sm = {0.f, 0.f, 0.f, 0.f};
    auto samplePoint = [&](float gx, float gy) {
      const float fx = (gx + 1.f) * 0.5f * 63.f;
      const float fy = (gy + 1.f) * 0.5f * 63.f;
      const float x0 = floorf(fx), y0 = floorf(fy);
      const float wx1 = fx - x0, wx0 = 1.f - wx1;
      const float wy1 = fy - y0, wy0 = 1.f - wy1;
#pragma unroll
      for (int cy = 0; cy < 2; ++cy) {
        const float yy = y0 + (float)cy;
        const float wy = cy ? wy1 : wy0;
        if (yy < 0.f || yy > 63.f || wy == 0.f) continue;
#pragma unroll
        for (int cx = 0; cx < 2; ++cx) {
          const float xx = x0 + (float)cx;
          const float wc = wy * (cx ? wx1 : wx0);
          if (xx < 0.f || xx > 63.f || wc == 0.f) continue;
          const int ri = (int)yy * WF_ + (int)xx;
          if constexpr (sizeof(FT) == 2) {
            const ushort4_t f4 =
                *(const ushort4_t*)&fb[(size_t)ri * 256 + lane * 4];
            sm.x += wc * b2f(f4.x);
            sm.y += wc * b2f(f4.y);
            sm.z += wc * b2f(f4.z);
            sm.w += wc * b2f(f4.w);
          } else {
            const float4 f4 = *(const float4*)&fb[(size_t)ri * 256 + lane * 4];
            sm.x += wc * f4.x;
            sm.y += wc * f4.y;
            sm.z += wc * f4.z;
            sm.w += wc * f4.w;
          }
        }
      }
    };
    if (same) {
      samplePoint(pcx[c] + offv[0], pcy[c] + offv[1]);
    } else {
#pragma unroll
      for (int p = 0; p < 4; ++p)
        samplePoint(pcx[c] + offv[2 * p], pcy[c] + offv[2 * p + 1]);
      sm.x *= 0.25f; sm.y *= 0.25f; sm.z *= 0.25f; sm.w *= 0.25f;
    }
    smc[c] = sm;
  }

  // 7 interleaved butterfly reductions
  float vals[7];
  vals[0] = dpg0;
#pragma unroll
  for (int c = 0; c < 6; ++c)
    vals[1 + c] = t0 * smc[c].x + t1 * smc[c].y + t2 * smc[c].z + t3 * smc[c].w;
#pragma unroll
  for (int o = 32; o > 0; o >>= 1) {
#pragma unroll
    for (int i = 0; i < 7; ++i) vals[i] += __shfl_xor(vals[i], o, 64);
  }
  const float gam = vals[0] + bqbk[0];

  float4 sv = {0.f, 0.f, 0.f, 0.f};
  float wsum = 0.f;
  int vcnt = 0;
#pragma unroll
  for (int c = 0; c < 6; ++c) {
    if (!validc[c]) continue;
    const float w = (vals[1 + c] + gam) * (1.f / 16.f);
    sv.x += w * smc[c].x;
    sv.y += w * smc[c].y;
    sv.z += w * smc[c].z;
    sv.w += w * smc[c].w;
    wsum += w;
    ++vcnt;
  }
  const float inv = 1.f / fmaxf((float)vcnt, 1.f);
  ushort4_t o;
  o.x = f2b(sv.x * inv); o.y = f2b(sv.y * inv);
  o.z = f2b(sv.z * inv); o.w = f2b(sv.w * inv);
  *(ushort4_t*)&SVb[(size_t)m * 256 + lane * 4] = o;
  if (lane == 0) wscale[m] = wsum * inv;
}

// ---------------------------------------------------------------------------
extern "C" void kernel_launch(void* const* d_in, const int* in_sizes, int n_in,
                              void* d_out, int out_size, void* d_ws,
                              size_t ws_size, hipStream_t stream) {
  const float* queries = (const float*)d_in[0];
  const float* feats = (const float*)d_in[1];
  const float* pix = (const float*)d_in[2];
  const int* vmask = (const int*)d_in[3];
  const float* Wq = (const float*)d_in[4];
  const float* bq = (const float*)d_in[5];
  const float* Wk = (const float*)d_in[6];
  const float* bk = (const float*)d_in[7];
  const float* Wv = (const float*)d_in[8];
  const float* bv = (const float*)d_in[9];
  const float* Wo = (const float*)d_in[10];
  const float* bo = (const float*)d_in[11];
  const float* Woff = (const float*)d_in[12];
  const float* boff = (const float*)d_in[13];
  const float* ln_g = (const float*)d_in[14];
  const float* ln_b = (const float*)d_in[15];

  char* w = (char*)d_ws;
  ushort_t* At = (ushort_t*)w;   w += 256 * 256 * 2;
  ushort_t* W2t = (ushort_t*)w;  w += 256 * 256 * 2;
  float* vec1 = (float*)w;       w += 1024;
  float* vec2 = (float*)w;       w += 1024;
  float* beta = (float*)w;       w += 1024;
  float* bqbk = (float*)w;       w += 256;
  float* OFFS = (float*)w;       w += (size_t)BN_ * 8 * 4;
  float* WSC = (float*)w;        w += (size_t)BN_ * 4;
  ushort_t* QNb = (ushort_t*)w;  w += (size_t)BN_ * 256 * 2;  // SVb overlays
  ushort_t* SVb = QNb;
  ushort_t* featb = (ushort_t*)w;
  const size_t featElems = (size_t)B_ * C_ * HF_ * WF_ * 256;  // 12,582,912
  const size_t need = (size_t)(w - (char*)d_ws) + featElems * 2;
  const bool useBf16Feat = (ws_size >= need);
  const int cvtBlocks = useBf16Feat ? (int)(featElems / 1024) : 0;

  ushort_t* Tb = (ushort_t*)d_out;  // bf16 T lives in d_out until final GEMM
  float* out = (float*)d_out;

  k_pre<<<cvtBlocks + 513 + BN_ / 4, 256, 0, stream>>>(
      feats, featb, Wq, Wk, Wv, Wo, bq, bk, bv, At, W2t, vec1, vec2, beta,
      bqbk, queries, ln_g, ln_b, Woff, boff, QNb, OFFS, cvtBlocks);
  k_gemm<0><<<256, 256, 0, stream>>>(QNb, At, (void*)Tb, vec1, nullptr,
                                     nullptr, nullptr, nullptr);
  if (useBf16Feat)
    k_sample<ushort_t><<<BN_ / 4, 256, 0, stream>>>(
        featb, pix, vmask, Tb, QNb, vec2, bqbk, OFFS, SVb, WSC);
  else
    k_sample<float><<<BN_ / 4, 256, 0, stream>>>(
        feats, pix, vmask, Tb, QNb, vec2, bqbk, OFFS, SVb, WSC);
  k_gemm<1><<<256, 256, 0, stream>>>(SVb, W2t, (void*)out, nullptr, queries,
                                     WSC, beta, bo);
}

// Round 5
// 97.103 us; speedup vs baseline: 2.0954x; 1.0426x over previous
//
#include <hip/hip_runtime.h>
#include <hip/hip_bf16.h>
#include <math.h>

#define B_   2
#define N_   8192
#define D_   256
#define C_   6
#define HF_  64
#define WF_  64
#define P_   4
#define BN_  (B_ * N_)   // 16384

typedef __attribute__((ext_vector_type(8))) short short8v;   // 8 bf16 (4 VGPRs)
typedef __attribute__((ext_vector_type(4))) float floatx4;

typedef unsigned short ushort_t;

struct ushort4_t { ushort_t x, y, z, w; };

__device__ __forceinline__ float wred64(float v) {
#pragma unroll
  for (int o = 32; o > 0; o >>= 1) v += __shfl_xor(v, o, 64);
  return v;
}

__device__ __forceinline__ ushort_t f2b(float x) {
  union { float f; unsigned u; } c;
  c.f = x;
  unsigned r = c.u + 0x7FFFu + ((c.u >> 16) & 1u);
  return (ushort_t)(r >> 16);
}

__device__ __forceinline__ float b2f(ushort_t u) {
  union { unsigned u; float f; } c;
  c.u = ((unsigned)u) << 16;
  return c.f;
}

// ---------------------------------------------------------------------------
// K1: merged pre-pass. Blocks [0,513): weight precompute (LONG serial loops
// first so they overlap the LN BW phase). Blocks [513, 513+4096): LayerNorm.
//   At[j][i]  = sum_o Wq[o][i] Wk[o][j]        (bf16, [n][k] for GEMM0 B-op)
//   W2t[d][e] = sum_m Wo[d][m] Wv[m][e]        (bf16, [n][k] for GEMM1 B-op)
//   vec1 = Wk^T bq ; vec2 = Wq^T bk ; beta = Wo bv ; bqbk = bq.bk
// ---------------------------------------------------------------------------
__global__ __launch_bounds__(256) void k_pre(
    const float* __restrict__ Wq, const float* __restrict__ Wk,
    const float* __restrict__ Wv, const float* __restrict__ Wo,
    const float* __restrict__ bq, const float* __restrict__ bk,
    const float* __restrict__ bv,
    ushort_t* __restrict__ At, ushort_t* __restrict__ W2t,
    float* __restrict__ vec1, float* __restrict__ vec2,
    float* __restrict__ beta, float* __restrict__ bqbk,
    const float* __restrict__ Q, const float* __restrict__ ln_g,
    const float* __restrict__ ln_b, const float* __restrict__ Woff,
    const float* __restrict__ boff, ushort_t* __restrict__ QNb,
    float* __restrict__ OFFS) {
  const int blk = blockIdx.x;
  const int t = threadIdx.x;
  if (blk < 513) {
    const int i = t;
    if (blk < 256) {
      const int j = blk;
      float a0 = 0.f, a1 = 0.f, a2 = 0.f, a3 = 0.f;
      for (int m = 0; m < 256; m += 4) {
        a0 += Wq[(m + 0) * 256 + i] * Wk[(m + 0) * 256 + j];
        a1 += Wq[(m + 1) * 256 + i] * Wk[(m + 1) * 256 + j];
        a2 += Wq[(m + 2) * 256 + i] * Wk[(m + 2) * 256 + j];
        a3 += Wq[(m + 3) * 256 + i] * Wk[(m + 3) * 256 + j];
      }
      At[j * 256 + i] = f2b((a0 + a1) + (a2 + a3));
    } else if (blk < 512) {
      const int d = blk - 256;
      float a0 = 0.f, a1 = 0.f, a2 = 0.f, a3 = 0.f;
      for (int m = 0; m < 256; m += 4) {
        a0 += Wo[d * 256 + m + 0] * Wv[(m + 0) * 256 + i];
        a1 += Wo[d * 256 + m + 1] * Wv[(m + 1) * 256 + i];
        a2 += Wo[d * 256 + m + 2] * Wv[(m + 2) * 256 + i];
        a3 += Wo[d * 256 + m + 3] * Wv[(m + 3) * 256 + i];
      }
      W2t[d * 256 + i] = f2b((a0 + a1) + (a2 + a3));
    } else {
      float a2 = 0.f, a1 = 0.f, ab = 0.f;
      for (int m = 0; m < 256; ++m) {
        a2 += Wq[m * 256 + i] * bk[m];
        a1 += Wk[m * 256 + i] * bq[m];
        ab += Wo[i * 256 + m] * bv[m];
      }
      vec2[i] = a2;
      vec1[i] = a1;
      beta[i] = ab;
      if (i == 0) {
        float s = 0.f;
        for (int m = 0; m < 256; ++m) s += bq[m] * bk[m];
        *bqbk = s;
      }
    }
    return;
  }
  // ---- LayerNorm + offsets
  const int lb = blk - 513;
  const int wave = t >> 6, lane = t & 63;
  const int m = lb * 4 + wave;
  const int base = m * 256 + lane * 4;
  const float4 x = *(const float4*)&Q[base];
  float s = x.x + x.y + x.z + x.w;
  float sq = x.x * x.x + x.y * x.y + x.z * x.z + x.w * x.w;
  s = wred64(s);
  sq = wred64(sq);
  const float mu = s * (1.0f / 256.0f);
  const float var = sq * (1.0f / 256.0f) - mu * mu;
  const float rs = rsqrtf(var + 1e-5f);
  const float4 g = *(const float4*)&ln_g[lane * 4];
  const float4 bb = *(const float4*)&ln_b[lane * 4];
  float4 y;
  y.x = (x.x - mu) * rs * g.x + bb.x;
  y.y = (x.y - mu) * rs * g.y + bb.y;
  y.z = (x.z - mu) * rs * g.z + bb.z;
  y.w = (x.w - mu) * rs * g.w + bb.w;
  ushort4_t qo;
  qo.x = f2b(y.x); qo.y = f2b(y.y); qo.z = f2b(y.z); qo.w = f2b(y.w);
  *(ushort4_t*)&QNb[base] = qo;
#pragma unroll
  for (int p2 = 0; p2 < 8; ++p2) {
    const float4 w = *(const float4*)&Woff[p2 * 256 + lane * 4];
    const float o = wred64(w.x * y.x + w.y * y.y + w.z * y.z + w.w * y.w);
    if (lane == 0) OFFS[m * 8 + p2] = (o + boff[p2]) * 0.05f;
  }
}

// ---------------------------------------------------------------------------
// bf16 MFMA GEMM: Y[16384 x 256] = Xb[16384 x 256] @ Wt^T  (Wt is [n][k])
// BM=BN=128, BK=64, 256 threads = 4 waves (2x2), each wave 64x64 (4x4 frags).
// Epilogue: per-wave 16x16 LDS transpose -> vectorized stores.
// MODE 0: Y = bf16(acc + vec1[col])
// MODE 1: Y = f32(acc + resid + wsc[row]*beta[col] + bo[col])
// ---------------------------------------------------------------------------
template <int MODE>
__global__ __launch_bounds__(256) void k_gemm(
    const ushort_t* __restrict__ Xb, const ushort_t* __restrict__ Wt,
    void* __restrict__ Yout, const float* __restrict__ vec1,
    const float* __restrict__ resid, const float* __restrict__ wsc,
    const float* __restrict__ beta, const float* __restrict__ bo) {
  __shared__ ushort_t As[128 * 68];  // rows padded 64->68 shorts (136B)
  __shared__ ushort_t Bs[128 * 68];
  __shared__ float tr[4][16 * 17];   // per-wave transpose buffer
  const int t = threadIdx.x;
  const int mb = blockIdx.x >> 1, nb = blockIdx.x & 1;
  const int m0 = mb * 128, n0 = nb * 128;
  const int wid = t >> 6, lane = t & 63;
  const int wm = wid >> 1, wn = wid & 1;
  const int lr = lane & 15, lh = lane >> 4;  // lh in 0..3

  floatx4 acc[4][4];
#pragma unroll
  for (int i = 0; i < 4; ++i)
#pragma unroll
    for (int j = 0; j < 4; ++j) acc[i][j] = (floatx4){0.f, 0.f, 0.f, 0.f};

  for (int k0 = 0; k0 < 256; k0 += 64) {
#pragma unroll
    for (int q = 0; q < 4; ++q) {
      const int s = t * 4 + q;
      const int row = s >> 3;
      const int off = (s & 7) * 8;  // shorts
      *(float4*)&As[row * 68 + off] =
          *(const float4*)(Xb + (size_t)(m0 + row) * 256 + k0 + off);
      *(float4*)&Bs[row * 68 + off] =
          *(const float4*)(Wt + (size_t)(n0 + row) * 256 + k0 + off);
    }
    __syncthreads();
#pragma unroll
    for (int kk = 0; kk < 64; kk += 32) {
      short8v a[4], b[4];
#pragma unroll
      for (int mi = 0; mi < 4; ++mi)
        a[mi] = *(const short8v*)&As[(wm * 64 + mi * 16 + lr) * 68 + kk + lh * 8];
#pragma unroll
      for (int ni = 0; ni < 4; ++ni)
        b[ni] = *(const short8v*)&Bs[(wn * 64 + ni * 16 + lr) * 68 + kk + lh * 8];
#pragma unroll
      for (int mi = 0; mi < 4; ++mi)
#pragma unroll
        for (int ni = 0; ni < 4; ++ni)
          acc[mi][ni] = __builtin_amdgcn_mfma_f32_16x16x32_bf16(
              a[mi], b[ni], acc[mi][ni], 0, 0, 0);
    }
    __syncthreads();
  }

  float* tb = tr[wid];
#pragma unroll
  for (int mi = 0; mi < 4; ++mi) {
#pragma unroll
    for (int ni = 0; ni < 4; ++ni) {
#pragma unroll
      for (int r = 0; r < 4; ++r)
        tb[(lh * 4 + r) * 17 + lr] = acc[mi][ni][r];
      const float4 v = *(const float4*)&tb[lr * 17 + lh * 4];
      const int row = m0 + wm * 64 + mi * 16 + lr;
      const int col = n0 + wn * 64 + ni * 16 + lh * 4;
      if (MODE == 0) {
        const float4 vc = *(const float4*)&vec1[col];
        ushort4_t o;
        o.x = f2b(v.x + vc.x);
        o.y = f2b(v.y + vc.y);
        o.z = f2b(v.z + vc.z);
        o.w = f2b(v.w + vc.w);
        *(ushort4_t*)((ushort_t*)Yout + (size_t)row * 256 + col) = o;
      } else {
        const float4 rv = *(const float4*)&resid[(size_t)row * 256 + col];
        const float4 bt = *(const float4*)&beta[col];
        const float4 bv4 = *(const float4*)&bo[col];
        const float wscale = wsc[row];
        float4 o;
        o.x = v.x + rv.x + wscale * bt.x + bv4.x;
        o.y = v.y + rv.y + wscale * bt.y + bv4.y;
        o.z = v.z + rv.z + wscale * bt.z + bv4.z;
        o.w = v.w + rv.w + wscale * bt.w + bv4.w;
        *(float4*)((float*)Yout + (size_t)row * 256 + col) = o;
      }
    }
  }
}

// ---------------------------------------------------------------------------
// Fused sampling + scores + aggregation. Wave per query; all cameras kept
// in registers; gathers for all valid cameras issued before any reduction;
// 7 butterfly reductions (6 camera dots + gamma dot) interleaved.
// Samples f32 features directly (L3-resident; no cvt pass).
// ---------------------------------------------------------------------------
__global__ __launch_bounds__(256) void k_sample(
    const float* __restrict__ feats, const float* __restrict__ pix,
    const int* __restrict__ vmask, const ushort_t* __restrict__ Tb,
    const ushort_t* __restrict__ QNb, const float* __restrict__ vec2,
    const float* __restrict__ bqbk, const float* __restrict__ OFFS,
    ushort_t* __restrict__ SVb, float* __restrict__ wscale) {
  const int wave = threadIdx.x >> 6, lane = threadIdx.x & 63;
  const int m = blockIdx.x * 4 + wave;
  const int b = m >> 13, n = m & 8191;

  const ushort4_t tu = *(const ushort4_t*)&Tb[(size_t)m * 256 + lane * 4];
  const float t0 = b2f(tu.x), t1 = b2f(tu.y), t2 = b2f(tu.z), t3 = b2f(tu.w);
  const ushort4_t qu = *(const ushort4_t*)&QNb[(size_t)m * 256 + lane * 4];
  const float4 v2 = *(const float4*)&vec2[lane * 4];
  const float dpg0 = v2.x * b2f(qu.x) + v2.y * b2f(qu.y) +
                     v2.z * b2f(qu.z) + v2.w * b2f(qu.w);

  float offv[8];
#pragma unroll
  for (int p2 = 0; p2 < 8; ++p2) offv[p2] = OFFS[m * 8 + p2];
  const bool same = (offv[0] == offv[2]) && (offv[0] == offv[4]) &&
                    (offv[0] == offv[6]) && (offv[1] == offv[3]) &&
                    (offv[1] == offv[5]) && (offv[1] == offv[7]);

  int validc[6];
  float pcx[6], pcy[6];
#pragma unroll
  for (int c = 0; c < 6; ++c) {
    const int idx = (b * 6 + c) * 8192 + n;
    validc[c] = vmask[idx];
    pcx[c] = 0.f;
    pcy[c] = 0.f;
    if (validc[c]) {
      pcx[c] = pix[(size_t)idx * 2 + 0];
      pcy[c] = pix[(size_t)idx * 2 + 1];
    }
  }

  float4 smc[6];
#pragma unroll
  for (int c = 0; c < 6; ++c) {
    smc[c] = (float4){0.f, 0.f, 0.f, 0.f};
    if (!validc[c]) continue;
    const float* fb = feats + (size_t)(b * 6 + c) * (HF_ * WF_ * 256);
    float4 sm = {0.f, 0.f, 0.f, 0.f};
    auto samplePoint = [&](float gx, float gy) {
      const float fx = (gx + 1.f) * 0.5f * 63.f;
      const float fy = (gy + 1.f) * 0.5f * 63.f;
      const float x0 = floorf(fx), y0 = floorf(fy);
      const float wx1 = fx - x0, wx0 = 1.f - wx1;
      const float wy1 = fy - y0, wy0 = 1.f - wy1;
#pragma unroll
      for (int cy = 0; cy < 2; ++cy) {
        const float yy = y0 + (float)cy;
        const float wy = cy ? wy1 : wy0;
        if (yy < 0.f || yy > 63.f || wy == 0.f) continue;
#pragma unroll
        for (int cx = 0; cx < 2; ++cx) {
          const float xx = x0 + (float)cx;
          const float wc = wy * (cx ? wx1 : wx0);
          if (xx < 0.f || xx > 63.f || wc == 0.f) continue;
          const int ri = (int)yy * WF_ + (int)xx;
          const float4 f4 = *(const float4*)&fb[(size_t)ri * 256 + lane * 4];
          sm.x += wc * f4.x;
          sm.y += wc * f4.y;
          sm.z += wc * f4.z;
          sm.w += wc * f4.w;
        }
      }
    };
    if (same) {
      samplePoint(pcx[c] + offv[0], pcy[c] + offv[1]);
    } else {
#pragma unroll
      for (int p = 0; p < 4; ++p)
        samplePoint(pcx[c] + offv[2 * p], pcy[c] + offv[2 * p + 1]);
      sm.x *= 0.25f; sm.y *= 0.25f; sm.z *= 0.25f; sm.w *= 0.25f;
    }
    smc[c] = sm;
  }

  // 7 interleaved butterfly reductions
  float vals[7];
  vals[0] = dpg0;
#pragma unroll
  for (int c = 0; c < 6; ++c)
    vals[1 + c] = t0 * smc[c].x + t1 * smc[c].y + t2 * smc[c].z + t3 * smc[c].w;
#pragma unroll
  for (int o = 32; o > 0; o >>= 1) {
#pragma unroll
    for (int i = 0; i < 7; ++i) vals[i] += __shfl_xor(vals[i], o, 64);
  }
  const float gam = vals[0] + bqbk[0];

  float4 sv = {0.f, 0.f, 0.f, 0.f};
  float wsum = 0.f;
  int vcnt = 0;
#pragma unroll
  for (int c = 0; c < 6; ++c) {
    if (!validc[c]) continue;
    const float w = (vals[1 + c] + gam) * (1.f / 16.f);
    sv.x += w * smc[c].x;
    sv.y += w * smc[c].y;
    sv.z += w * smc[c].z;
    sv.w += w * smc[c].w;
    wsum += w;
    ++vcnt;
  }
  const float inv = 1.f / fmaxf((float)vcnt, 1.f);
  ushort4_t o;
  o.x = f2b(sv.x * inv); o.y = f2b(sv.y * inv);
  o.z = f2b(sv.z * inv); o.w = f2b(sv.w * inv);
  *(ushort4_t*)&SVb[(size_t)m * 256 + lane * 4] = o;
  if (lane == 0) wscale[m] = wsum * inv;
}

// ---------------------------------------------------------------------------
extern "C" void kernel_launch(void* const* d_in, const int* in_sizes, int n_in,
                              void* d_out, int out_size, void* d_ws,
                              size_t ws_size, hipStream_t stream) {
  const float* queries = (const float*)d_in[0];
  const float* feats = (const float*)d_in[1];
  const float* pix = (const float*)d_in[2];
  const int* vmask = (const int*)d_in[3];
  const float* Wq = (const float*)d_in[4];
  const float* bq = (const float*)d_in[5];
  const float* Wk = (const float*)d_in[6];
  const float* bk = (const float*)d_in[7];
  const float* Wv = (const float*)d_in[8];
  const float* bv = (const float*)d_in[9];
  const float* Wo = (const float*)d_in[10];
  const float* bo = (const float*)d_in[11];
  const float* Woff = (const float*)d_in[12];
  const float* boff = (const float*)d_in[13];
  const float* ln_g = (const float*)d_in[14];
  const float* ln_b = (const float*)d_in[15];

  char* w = (char*)d_ws;
  ushort_t* At = (ushort_t*)w;   w += 256 * 256 * 2;
  ushort_t* W2t = (ushort_t*)w;  w += 256 * 256 * 2;
  float* vec1 = (float*)w;       w += 1024;
  float* vec2 = (float*)w;       w += 1024;
  float* beta = (float*)w;       w += 1024;
  float* bqbk = (float*)w;       w += 256;
  float* OFFS = (float*)w;       w += (size_t)BN_ * 8 * 4;
  float* WSC = (float*)w;        w += (size_t)BN_ * 4;
  ushort_t* QNb = (ushort_t*)w;  w += (size_t)BN_ * 256 * 2;  // SVb overlays
  ushort_t* SVb = QNb;

  ushort_t* Tb = (ushort_t*)d_out;  // bf16 T lives in d_out until final GEMM
  float* out = (float*)d_out;

  k_pre<<<513 + BN_ / 4, 256, 0, stream>>>(
      Wq, Wk, Wv, Wo, bq, bk, bv, At, W2t, vec1, vec2, beta, bqbk,
      queries, ln_g, ln_b, Woff, boff, QNb, OFFS);
  k_gemm<0><<<256, 256, 0, stream>>>(QNb, At, (void*)Tb, vec1, nullptr,
                                     nullptr, nullptr, nullptr);
  k_sample<<<BN_ / 4, 256, 0, stream>>>(feats, pix, vmask, Tb, QNb, vec2,
                                        bqbk, OFFS, SVb, WSC);
  k_gemm<1><<<256, 256, 0, stream>>>(SVb, W2t, (void*)out, nullptr, queries,
                                     WSC, beta, bo);
}

// Round 6
// 92.498 us; speedup vs baseline: 2.1997x; 1.0498x over previous
//
#include <hip/hip_runtime.h>
#include <hip/hip_bf16.h>
#include <math.h>

#define B_   2
#define N_   8192
#define D_   256
#define C_   6
#define HF_  64
#define WF_  64
#define P_   4
#define BN_  (B_ * N_)   // 16384

typedef __attribute__((ext_vector_type(8))) short short8v;   // 8 bf16 (4 VGPRs)
typedef __attribute__((ext_vector_type(4))) float floatx4;

typedef unsigned short ushort_t;

struct ushort4_t { ushort_t x, y, z, w; };

__device__ __forceinline__ float wred64(float v) {
#pragma unroll
  for (int o = 32; o > 0; o >>= 1) v += __shfl_xor(v, o, 64);
  return v;
}

__device__ __forceinline__ ushort_t f2b(float x) {
  union { float f; unsigned u; } c;
  c.f = x;
  unsigned r = c.u + 0x7FFFu + ((c.u >> 16) & 1u);
  return (ushort_t)(r >> 16);
}

__device__ __forceinline__ float b2f(ushort_t u) {
  union { unsigned u; float f; } c;
  c.u = ((unsigned)u) << 16;
  return c.f;
}

// ---------------------------------------------------------------------------
// K1 merged pre-pass.
//  blocks 0..7 : weight products via MFMA (128x128 tiles):
//     prod 0 (blk 0..3): At[j][i]  = sum_m Wk[m][j] * Wq[m][i]
//     prod 1 (blk 4..7): W2t[d][e] = sum_m Wo[d][m] * Wv[m][e]
//  block 8     : vec1 = Wk^T bq ; vec2 = Wq^T bk ; beta = Wo bv ; bqbk
//  blocks 9..  : LayerNorm -> QNb (bf16) + OFFS
// ---------------------------------------------------------------------------
__global__ __launch_bounds__(256) void k_pre(
    const float* __restrict__ Wq, const float* __restrict__ Wk,
    const float* __restrict__ Wv, const float* __restrict__ Wo,
    const float* __restrict__ bq, const float* __restrict__ bk,
    const float* __restrict__ bv,
    ushort_t* __restrict__ At, ushort_t* __restrict__ W2t,
    float* __restrict__ vec1, float* __restrict__ vec2,
    float* __restrict__ beta, float* __restrict__ bqbk,
    const float* __restrict__ Q, const float* __restrict__ ln_g,
    const float* __restrict__ ln_b, const float* __restrict__ Woff,
    const float* __restrict__ boff, ushort_t* __restrict__ QNb,
    float* __restrict__ OFFS) {
  __shared__ ushort_t Ak[128 * 68];
  __shared__ ushort_t Bk[128 * 68];
  const int blk = blockIdx.x;
  const int t = threadIdx.x;

  if (blk < 8) {
    const int prod = blk >> 2;
    const int tb = blk & 3;
    const int rb = (tb >> 1) * 128;  // output row base (j or d)
    const int cb = (tb & 1) * 128;   // output col base (i or e)
    const int wid = t >> 6, lane = t & 63;
    const int wm = wid >> 1, wn = wid & 1;
    const int lr = lane & 15, lh = lane >> 4;
    floatx4 acc[4][4];
#pragma unroll
    for (int i = 0; i < 4; ++i)
#pragma unroll
      for (int j = 0; j < 4; ++j) acc[i][j] = (floatx4){0.f, 0.f, 0.f, 0.f};

    for (int m0 = 0; m0 < 256; m0 += 64) {
      if (prod == 0) {
        // A rows j <- Wk columns (transpose stage); B cols i <- Wq columns
#pragma unroll
        for (int seg = 0; seg < 8; ++seg) {
          const int mm = (t >> 5) + seg * 8;   // 0..63
          const int cc = (t & 31) * 4;         // 0..124
          const float4 va = *(const float4*)&Wk[(m0 + mm) * 256 + rb + cc];
          Ak[(cc + 0) * 68 + mm] = f2b(va.x);
          Ak[(cc + 1) * 68 + mm] = f2b(va.y);
          Ak[(cc + 2) * 68 + mm] = f2b(va.z);
          Ak[(cc + 3) * 68 + mm] = f2b(va.w);
          const float4 vb = *(const float4*)&Wq[(m0 + mm) * 256 + cb + cc];
          Bk[(cc + 0) * 68 + mm] = f2b(vb.x);
          Bk[(cc + 1) * 68 + mm] = f2b(vb.y);
          Bk[(cc + 2) * 68 + mm] = f2b(vb.z);
          Bk[(cc + 3) * 68 + mm] = f2b(vb.w);
        }
      } else {
        // A rows d: Wo[d][m] straight; B cols e <- Wv columns (transpose)
#pragma unroll
        for (int seg = 0; seg < 8; ++seg) {
          const int s = t + seg * 256;
          const int row = s >> 4;          // 0..127
          const int c4 = (s & 15) * 4;     // 0..60
          const float4 va = *(const float4*)&Wo[(rb + row) * 256 + m0 + c4];
          ushort4_t pa;
          pa.x = f2b(va.x); pa.y = f2b(va.y); pa.z = f2b(va.z); pa.w = f2b(va.w);
          *(ushort4_t*)&Ak[row * 68 + c4] = pa;
          const int mm = (t >> 5) + seg * 8;
          const int cc = (t & 31) * 4;
          const float4 vb = *(const float4*)&Wv[(m0 + mm) * 256 + cb + cc];
          Bk[(cc + 0) * 68 + mm] = f2b(vb.x);
          Bk[(cc + 1) * 68 + mm] = f2b(vb.y);
          Bk[(cc + 2) * 68 + mm] = f2b(vb.z);
          Bk[(cc + 3) * 68 + mm] = f2b(vb.w);
        }
      }
      __syncthreads();
#pragma unroll
      for (int kk = 0; kk < 64; kk += 32) {
        short8v a[4], b[4];
#pragma unroll
        for (int mi = 0; mi < 4; ++mi)
          a[mi] = *(const short8v*)&Ak[(wm * 64 + mi * 16 + lr) * 68 + kk + lh * 8];
#pragma unroll
        for (int ni = 0; ni < 4; ++ni)
          b[ni] = *(const short8v*)&Bk[(wn * 64 + ni * 16 + lr) * 68 + kk + lh * 8];
#pragma unroll
        for (int mi = 0; mi < 4; ++mi)
#pragma unroll
          for (int ni = 0; ni < 4; ++ni)
            acc[mi][ni] = __builtin_amdgcn_mfma_f32_16x16x32_bf16(
                a[mi], b[ni], acc[mi][ni], 0, 0, 0);
      }
      __syncthreads();
    }
    ushort_t* dst = prod ? W2t : At;
#pragma unroll
    for (int mi = 0; mi < 4; ++mi)
#pragma unroll
      for (int ni = 0; ni < 4; ++ni)
#pragma unroll
        for (int r = 0; r < 4; ++r)
          dst[(size_t)(rb + wm * 64 + mi * 16 + lh * 4 + r) * 256 +
              cb + wn * 64 + ni * 16 + lr] = f2b(acc[mi][ni][r]);
    return;
  }

  if (blk == 8) {
    const int i = t;
    float a2 = 0.f, a1 = 0.f, ab = 0.f;
    for (int m = 0; m < 256; ++m) {
      a2 += Wq[m * 256 + i] * bk[m];
      a1 += Wk[m * 256 + i] * bq[m];
      ab += Wo[i * 256 + m] * bv[m];
    }
    vec2[i] = a2;
    vec1[i] = a1;
    beta[i] = ab;
    if (i == 0) {
      float s = 0.f;
      for (int m = 0; m < 256; ++m) s += bq[m] * bk[m];
      *bqbk = s;
    }
    return;
  }

  // ---- LayerNorm + offsets
  const int lb = blk - 9;
  const int wave = t >> 6, lane = t & 63;
  const int m = lb * 4 + wave;
  const int base = m * 256 + lane * 4;
  const float4 x = *(const float4*)&Q[base];
  float s = x.x + x.y + x.z + x.w;
  float sq = x.x * x.x + x.y * x.y + x.z * x.z + x.w * x.w;
  s = wred64(s);
  sq = wred64(sq);
  const float mu = s * (1.0f / 256.0f);
  const float var = sq * (1.0f / 256.0f) - mu * mu;
  const float rs = rsqrtf(var + 1e-5f);
  const float4 g = *(const float4*)&ln_g[lane * 4];
  const float4 bb = *(const float4*)&ln_b[lane * 4];
  float4 y;
  y.x = (x.x - mu) * rs * g.x + bb.x;
  y.y = (x.y - mu) * rs * g.y + bb.y;
  y.z = (x.z - mu) * rs * g.z + bb.z;
  y.w = (x.w - mu) * rs * g.w + bb.w;
  ushort4_t qo;
  qo.x = f2b(y.x); qo.y = f2b(y.y); qo.z = f2b(y.z); qo.w = f2b(y.w);
  *(ushort4_t*)&QNb[base] = qo;
#pragma unroll
  for (int p2 = 0; p2 < 8; ++p2) {
    const float4 w = *(const float4*)&Woff[p2 * 256 + lane * 4];
    const float o = wred64(w.x * y.x + w.y * y.y + w.z * y.z + w.w * y.w);
    if (lane == 0) OFFS[m * 8 + p2] = (o + boff[p2]) * 0.05f;
  }
}

// ---------------------------------------------------------------------------
// bf16 MFMA GEMM: Y[16384 x 256] = Xb @ Wt^T (Wt is [n][k]).
// 64x64 tiles -> 1024 blocks (4 blocks/CU). 4 waves (2x2), wave = 32x32.
// MODE 0: Y = bf16(acc + vec1[col]);  MODE 1: f32 out + resid + epilogue.
// ---------------------------------------------------------------------------
template <int MODE>
__global__ __launch_bounds__(256) void k_gemm(
    const ushort_t* __restrict__ Xb, const ushort_t* __restrict__ Wt,
    void* __restrict__ Yout, const float* __restrict__ vec1,
    const float* __restrict__ resid, const float* __restrict__ wsc,
    const float* __restrict__ beta, const float* __restrict__ bo) {
  __shared__ ushort_t As[64 * 68];
  __shared__ ushort_t Bs[64 * 68];
  __shared__ float tr[4][16 * 17];
  const int t = threadIdx.x;
  const int nb = blockIdx.x & 3, mb = blockIdx.x >> 2;
  const int m0 = mb * 64, n0 = nb * 64;
  const int wid = t >> 6, lane = t & 63;
  const int wm = wid >> 1, wn = wid & 1;
  const int lr = lane & 15, lh = lane >> 4;

  floatx4 acc[2][2];
#pragma unroll
  for (int i = 0; i < 2; ++i)
#pragma unroll
    for (int j = 0; j < 2; ++j) acc[i][j] = (floatx4){0.f, 0.f, 0.f, 0.f};

  for (int k0 = 0; k0 < 256; k0 += 64) {
#pragma unroll
    for (int q = 0; q < 2; ++q) {
      const int s = t * 2 + q;
      const int row = s >> 3;
      const int off = (s & 7) * 8;
      *(float4*)&As[row * 68 + off] =
          *(const float4*)(Xb + (size_t)(m0 + row) * 256 + k0 + off);
      *(float4*)&Bs[row * 68 + off] =
          *(const float4*)(Wt + (size_t)(n0 + row) * 256 + k0 + off);
    }
    __syncthreads();
#pragma unroll
    for (int kk = 0; kk < 64; kk += 32) {
      short8v a[2], b[2];
#pragma unroll
      for (int mi = 0; mi < 2; ++mi)
        a[mi] = *(const short8v*)&As[(wm * 32 + mi * 16 + lr) * 68 + kk + lh * 8];
#pragma unroll
      for (int ni = 0; ni < 2; ++ni)
        b[ni] = *(const short8v*)&Bs[(wn * 32 + ni * 16 + lr) * 68 + kk + lh * 8];
#pragma unroll
      for (int mi = 0; mi < 2; ++mi)
#pragma unroll
        for (int ni = 0; ni < 2; ++ni)
          acc[mi][ni] = __builtin_amdgcn_mfma_f32_16x16x32_bf16(
              a[mi], b[ni], acc[mi][ni], 0, 0, 0);
    }
    __syncthreads();
  }

  float* tb = tr[wid];
#pragma unroll
  for (int mi = 0; mi < 2; ++mi) {
#pragma unroll
    for (int ni = 0; ni < 2; ++ni) {
#pragma unroll
      for (int r = 0; r < 4; ++r)
        tb[(lh * 4 + r) * 17 + lr] = acc[mi][ni][r];
      const float4 v = *(const float4*)&tb[lr * 17 + lh * 4];
      const int row = m0 + wm * 32 + mi * 16 + lr;
      const int col = n0 + wn * 32 + ni * 16 + lh * 4;
      if (MODE == 0) {
        const float4 vc = *(const float4*)&vec1[col];
        ushort4_t o;
        o.x = f2b(v.x + vc.x);
        o.y = f2b(v.y + vc.y);
        o.z = f2b(v.z + vc.z);
        o.w = f2b(v.w + vc.w);
        *(ushort4_t*)((ushort_t*)Yout + (size_t)row * 256 + col) = o;
      } else {
        const float4 rv = *(const float4*)&resid[(size_t)row * 256 + col];
        const float4 bt = *(const float4*)&beta[col];
        const float4 bv4 = *(const float4*)&bo[col];
        const float wscale = wsc[row];
        float4 o;
        o.x = v.x + rv.x + wscale * bt.x + bv4.x;
        o.y = v.y + rv.y + wscale * bt.y + bv4.y;
        o.z = v.z + rv.z + wscale * bt.z + bv4.z;
        o.w = v.w + rv.w + wscale * bt.w + bv4.w;
        *(float4*)((float*)Yout + (size_t)row * 256 + col) = o;
      }
    }
  }
}

// ---------------------------------------------------------------------------
// Fused sampling + scores + aggregation. Wave per query; all cameras in
// registers; branchless bilinear corners (clamp index, zero weight);
// 7 interleaved butterfly reductions.
// ---------------------------------------------------------------------------
__global__ __launch_bounds__(256) void k_sample(
    const float* __restrict__ feats, const float* __restrict__ pix,
    const int* __restrict__ vmask, const ushort_t* __restrict__ Tb,
    const ushort_t* __restrict__ QNb, const float* __restrict__ vec2,
    const float* __restrict__ bqbk, const float* __restrict__ OFFS,
    ushort_t* __restrict__ SVb, float* __restrict__ wscale) {
  const int wave = threadIdx.x >> 6, lane = threadIdx.x & 63;
  const int m = blockIdx.x * 4 + wave;
  const int b = m >> 13, n = m & 8191;

  const ushort4_t tu = *(const ushort4_t*)&Tb[(size_t)m * 256 + lane * 4];
  const float t0 = b2f(tu.x), t1 = b2f(tu.y), t2 = b2f(tu.z), t3 = b2f(tu.w);
  const ushort4_t qu = *(const ushort4_t*)&QNb[(size_t)m * 256 + lane * 4];
  const float4 v2 = *(const float4*)&vec2[lane * 4];
  const float dpg0 = v2.x * b2f(qu.x) + v2.y * b2f(qu.y) +
                     v2.z * b2f(qu.z) + v2.w * b2f(qu.w);

  float offv[8];
  {
    const float4 o0 = *(const float4*)&OFFS[m * 8];
    const float4 o1 = *(const float4*)&OFFS[m * 8 + 4];
    offv[0] = o0.x; offv[1] = o0.y; offv[2] = o0.z; offv[3] = o0.w;
    offv[4] = o1.x; offv[5] = o1.y; offv[6] = o1.z; offv[7] = o1.w;
  }
  const bool same = (offv[0] == offv[2]) && (offv[0] == offv[4]) &&
                    (offv[0] == offv[6]) && (offv[1] == offv[3]) &&
                    (offv[1] == offv[5]) && (offv[1] == offv[7]);

  int validc[6];
  float pcx[6], pcy[6];
#pragma unroll
  for (int c = 0; c < 6; ++c) {
    const int idx = (b * 6 + c) * 8192 + n;
    validc[c] = vmask[idx];
    pcx[c] = pix[(size_t)idx * 2 + 0];
    pcy[c] = pix[(size_t)idx * 2 + 1];
  }

  float4 smc[6];
#pragma unroll
  for (int c = 0; c < 6; ++c) {
    smc[c] = (float4){0.f, 0.f, 0.f, 0.f};
    if (!validc[c]) continue;
    const float* fb = feats + (size_t)(b * 6 + c) * (HF_ * WF_ * 256);
    float4 sm = {0.f, 0.f, 0.f, 0.f};
    auto samplePoint = [&](float gx, float gy) {
      const float fx = (gx + 1.f) * 31.5f;
      const float fy = (gy + 1.f) * 31.5f;
      const float x0f = floorf(fx), y0f = floorf(fy);
      const float wx1 = fx - x0f, wx0 = 1.f - wx1;
      const float wy1 = fy - y0f, wy0 = 1.f - wy1;
      const int x0 = (int)x0f, y0 = (int)y0f;
#pragma unroll
      for (int cy = 0; cy < 2; ++cy) {
        const float yyf = y0f + (float)cy;
        const float vy = (yyf >= 0.f && yyf <= 63.f) ? 1.f : 0.f;
        const int yc = min(max(y0 + cy, 0), 63);
        const float wyv = (cy ? wy1 : wy0) * vy;
#pragma unroll
        for (int cx = 0; cx < 2; ++cx) {
          const float xxf = x0f + (float)cx;
          const float vx = (xxf >= 0.f && xxf <= 63.f) ? 1.f : 0.f;
          const int xc = min(max(x0 + cx, 0), 63);
          const float wv = wyv * (cx ? wx1 : wx0) * vx;
          const int ri = yc * WF_ + xc;
          const float4 f4 = *(const float4*)&fb[(size_t)ri * 256 + lane * 4];
          sm.x += wv * f4.x;
          sm.y += wv * f4.y;
          sm.z += wv * f4.z;
          sm.w += wv * f4.w;
        }
      }
    };
    if (same) {
      samplePoint(pcx[c] + offv[0], pcy[c] + offv[1]);
    } else {
#pragma unroll
      for (int p = 0; p < 4; ++p)
        samplePoint(pcx[c] + offv[2 * p], pcy[c] + offv[2 * p + 1]);
      sm.x *= 0.25f; sm.y *= 0.25f; sm.z *= 0.25f; sm.w *= 0.25f;
    }
    smc[c] = sm;
  }

  // 7 interleaved butterfly reductions
  float vals[7];
  vals[0] = dpg0;
#pragma unroll
  for (int c = 0; c < 6; ++c)
    vals[1 + c] = t0 * smc[c].x + t1 * smc[c].y + t2 * smc[c].z + t3 * smc[c].w;
#pragma unroll
  for (int o = 32; o > 0; o >>= 1) {
#pragma unroll
    for (int i = 0; i < 7; ++i) vals[i] += __shfl_xor(vals[i], o, 64);
  }
  const float gam = vals[0] + bqbk[0];

  float4 sv = {0.f, 0.f, 0.f, 0.f};
  float wsum = 0.f;
  int vcnt = 0;
#pragma unroll
  for (int c = 0; c < 6; ++c) {
    if (!validc[c]) continue;
    const float w = (vals[1 + c] + gam) * (1.f / 16.f);
    sv.x += w * smc[c].x;
    sv.y += w * smc[c].y;
    sv.z += w * smc[c].z;
    sv.w += w * smc[c].w;
    wsum += w;
    ++vcnt;
  }
  const float inv = 1.f / fmaxf((float)vcnt, 1.f);
  ushort4_t o;
  o.x = f2b(sv.x * inv); o.y = f2b(sv.y * inv);
  o.z = f2b(sv.z * inv); o.w = f2b(sv.w * inv);
  *(ushort4_t*)&SVb[(size_t)m * 256 + lane * 4] = o;
  if (lane == 0) wscale[m] = wsum * inv;
}

// ---------------------------------------------------------------------------
extern "C" void kernel_launch(void* const* d_in, const int* in_sizes, int n_in,
                              void* d_out, int out_size, void* d_ws,
                              size_t ws_size, hipStream_t stream) {
  const float* queries = (const float*)d_in[0];
  const float* feats = (const float*)d_in[1];
  const float* pix = (const float*)d_in[2];
  const int* vmask = (const int*)d_in[3];
  const float* Wq = (const float*)d_in[4];
  const float* bq = (const float*)d_in[5];
  const float* Wk = (const float*)d_in[6];
  const float* bk = (const float*)d_in[7];
  const float* Wv = (const float*)d_in[8];
  const float* bv = (const float*)d_in[9];
  const float* Wo = (const float*)d_in[10];
  const float* bo = (const float*)d_in[11];
  const float* Woff = (const float*)d_in[12];
  const float* boff = (const float*)d_in[13];
  const float* ln_g = (const float*)d_in[14];
  const float* ln_b = (const float*)d_in[15];

  char* w = (char*)d_ws;
  ushort_t* At = (ushort_t*)w;   w += 256 * 256 * 2;
  ushort_t* W2t = (ushort_t*)w;  w += 256 * 256 * 2;
  float* vec1 = (float*)w;       w += 1024;
  float* vec2 = (float*)w;       w += 1024;
  float* beta = (float*)w;       w += 1024;
  float* bqbk = (float*)w;       w += 256;
  float* OFFS = (float*)w;       w += (size_t)BN_ * 8 * 4;
  float* WSC = (float*)w;        w += (size_t)BN_ * 4;
  ushort_t* QNb = (ushort_t*)w;  w += (size_t)BN_ * 256 * 2;  // SVb overlays
  ushort_t* SVb = QNb;

  ushort_t* Tb = (ushort_t*)d_out;  // bf16 T lives in d_out until final GEMM
  float* out = (float*)d_out;

  k_pre<<<9 + BN_ / 4, 256, 0, stream>>>(
      Wq, Wk, Wv, Wo, bq, bk, bv, At, W2t, vec1, vec2, beta, bqbk,
      queries, ln_g, ln_b, Woff, boff, QNb, OFFS);
  k_gemm<0><<<BN_ / 64 * 4, 256, 0, stream>>>(QNb, At, (void*)Tb, vec1,
                                              nullptr, nullptr, nullptr,
                                              nullptr);
  k_sample<<<BN_ / 4, 256, 0, stream>>>(feats, pix, vmask, Tb, QNb, vec2,
                                        bqbk, OFFS, SVb, WSC);
  k_gemm<1><<<BN_ / 64 * 4, 256, 0, stream>>>(SVb, W2t, (void*)out, nullptr,
                                              queries, WSC, beta, bo);
}

// Round 7
// 86.617 us; speedup vs baseline: 2.3491x; 1.0679x over previous
//
#include <hip/hip_runtime.h>
#include <hip/hip_bf16.h>
#include <math.h>

#define B_   2
#define N_   8192
#define D_   256
#define C_   6
#define HF_  64
#define WF_  64
#define P_   4
#define BN_  (B_ * N_)   // 16384

typedef __attribute__((ext_vector_type(8))) short short8v;   // 8 bf16 (4 VGPRs)
typedef __attribute__((ext_vector_type(4))) float floatx4;

typedef unsigned short ushort_t;
// ext_vector => natural 8B alignment + .x/.y/.z/.w swizzles
typedef __attribute__((ext_vector_type(4))) unsigned short ushort4_t;

__device__ __forceinline__ float wred64(float v) {
#pragma unroll
  for (int o = 32; o > 0; o >>= 1) v += __shfl_xor(v, o, 64);
  return v;
}

__device__ __forceinline__ ushort_t f2b(float x) {
  union { float f; unsigned u; } c;
  c.f = x;
  unsigned r = c.u + 0x7FFFu + ((c.u >> 16) & 1u);
  return (ushort_t)(r >> 16);
}

__device__ __forceinline__ float b2f(ushort_t u) {
  union { unsigned u; float f; } c;
  c.u = ((unsigned)u) << 16;
  return c.f;
}

// ---------------------------------------------------------------------------
// K1 merged pre-pass (all blocks independent):
//  blocks [0,32)            : weight products via MFMA, 64x64 tiles
//     prod 0 (blk 0..15) : At[j][i]  = sum_m Wk[m][j] * Wq[m][i]
//     prod 1 (blk 16..31): W2t[d][e] = sum_m Wo[d][m] * Wv[m][e]
//  block 32                 : vec1/vec2/beta/bqbk
//  blocks [33, 33+NCVT)     : feature f32 -> bf16 conversion
//  blocks [33+NCVT, +4096)  : LayerNorm -> QNb (bf16) + OFFS
// ---------------------------------------------------------------------------
__global__ __launch_bounds__(256) void k_pre(
    const float* __restrict__ feats, ushort_t* __restrict__ featb,
    const float* __restrict__ Wq, const float* __restrict__ Wk,
    const float* __restrict__ Wv, const float* __restrict__ Wo,
    const float* __restrict__ bq, const float* __restrict__ bk,
    const float* __restrict__ bv,
    ushort_t* __restrict__ At, ushort_t* __restrict__ W2t,
    float* __restrict__ vec1, float* __restrict__ vec2,
    float* __restrict__ beta, float* __restrict__ bqbk,
    const float* __restrict__ Q, const float* __restrict__ ln_g,
    const float* __restrict__ ln_b, const float* __restrict__ Woff,
    const float* __restrict__ boff, ushort_t* __restrict__ QNb,
    float* __restrict__ OFFS, int cvtBlocks) {
  __shared__ ushort_t Ak[64 * 68];   // 8.7 KB
  __shared__ ushort_t Bk[64 * 68];   // 8.7 KB  (17.4 KB total -> 9 blocks/CU)
  const int blk = blockIdx.x;
  const int t = threadIdx.x;

  if (blk < 32) {
    const int prod = blk >> 4;
    const int tb = blk & 15;
    const int rb = (tb >> 2) * 64;   // output row base (j or d)
    const int cb = (tb & 3) * 64;    // output col base (i or e)
    const int wid = t >> 6, lane = t & 63;
    const int wm = wid >> 1, wn = wid & 1;
    const int lr = lane & 15, lh = lane >> 4;
    floatx4 acc[2][2];
#pragma unroll
    for (int i = 0; i < 2; ++i)
#pragma unroll
      for (int j = 0; j < 2; ++j) acc[i][j] = (floatx4){0.f, 0.f, 0.f, 0.f};

    for (int m0 = 0; m0 < 256; m0 += 64) {
      if (prod == 0) {
        // Ak[j][m] <- Wk[m][j] ; Bk[i][m] <- Wq[m][i]  (both transposed)
#pragma unroll
        for (int seg = 0; seg < 4; ++seg) {
          const int mm = (t >> 4) + seg * 16;  // 0..63
          const int cc = (t & 15) * 4;         // 0..60
          const float4 va = *(const float4*)&Wk[(m0 + mm) * 256 + rb + cc];
          Ak[(cc + 0) * 68 + mm] = f2b(va.x);
          Ak[(cc + 1) * 68 + mm] = f2b(va.y);
          Ak[(cc + 2) * 68 + mm] = f2b(va.z);
          Ak[(cc + 3) * 68 + mm] = f2b(va.w);
          const float4 vb = *(const float4*)&Wq[(m0 + mm) * 256 + cb + cc];
          Bk[(cc + 0) * 68 + mm] = f2b(vb.x);
          Bk[(cc + 1) * 68 + mm] = f2b(vb.y);
          Bk[(cc + 2) * 68 + mm] = f2b(vb.z);
          Bk[(cc + 3) * 68 + mm] = f2b(vb.w);
        }
      } else {
        // Ak[d][m] <- Wo[d][m] (straight) ; Bk[e][m] <- Wv[m][e] (transposed)
#pragma unroll
        for (int seg = 0; seg < 4; ++seg) {
          const int row = (t >> 4) + seg * 16;  // 0..63
          const int c4 = (t & 15) * 4;          // 0..60
          const float4 va = *(const float4*)&Wo[(rb + row) * 256 + m0 + c4];
          Ak[row * 68 + c4 + 0] = f2b(va.x);
          Ak[row * 68 + c4 + 1] = f2b(va.y);
          Ak[row * 68 + c4 + 2] = f2b(va.z);
          Ak[row * 68 + c4 + 3] = f2b(va.w);
          const float4 vb = *(const float4*)&Wv[(m0 + row) * 256 + cb + c4];
          Bk[(c4 + 0) * 68 + row] = f2b(vb.x);
          Bk[(c4 + 1) * 68 + row] = f2b(vb.y);
          Bk[(c4 + 2) * 68 + row] = f2b(vb.z);
          Bk[(c4 + 3) * 68 + row] = f2b(vb.w);
        }
      }
      __syncthreads();
#pragma unroll
      for (int kk = 0; kk < 64; kk += 32) {
        short8v a[2], b[2];
#pragma unroll
        for (int mi = 0; mi < 2; ++mi)
          a[mi] = *(const short8v*)&Ak[(wm * 32 + mi * 16 + lr) * 68 + kk + lh * 8];
#pragma unroll
        for (int ni = 0; ni < 2; ++ni)
          b[ni] = *(const short8v*)&Bk[(wn * 32 + ni * 16 + lr) * 68 + kk + lh * 8];
#pragma unroll
        for (int mi = 0; mi < 2; ++mi)
#pragma unroll
          for (int ni = 0; ni < 2; ++ni)
            acc[mi][ni] = __builtin_amdgcn_mfma_f32_16x16x32_bf16(
                a[mi], b[ni], acc[mi][ni], 0, 0, 0);
      }
      __syncthreads();
    }
    ushort_t* dst = prod ? W2t : At;
#pragma unroll
    for (int mi = 0; mi < 2; ++mi)
#pragma unroll
      for (int ni = 0; ni < 2; ++ni)
#pragma unroll
        for (int r = 0; r < 4; ++r)
          dst[(size_t)(rb + wm * 32 + mi * 16 + lh * 4 + r) * 256 +
              cb + wn * 32 + ni * 16 + lr] = f2b(acc[mi][ni][r]);
    return;
  }

  if (blk == 32) {
    const int i = t;
    float a2 = 0.f, a1 = 0.f, ab = 0.f;
    for (int m = 0; m < 256; ++m) {
      a2 += Wq[m * 256 + i] * bk[m];
      a1 += Wk[m * 256 + i] * bq[m];
      ab += Wo[i * 256 + m] * bv[m];
    }
    vec2[i] = a2;
    vec1[i] = a1;
    beta[i] = ab;
    if (i == 0) {
      float s = 0.f;
      for (int m = 0; m < 256; ++m) s += bq[m] * bk[m];
      *bqbk = s;
    }
    return;
  }

  if (blk < 33 + cvtBlocks) {
    // ---- feature conversion: 2048 elems per block, 8 per thread
    const size_t base = ((size_t)(blk - 33) * 256 + t) * 8;
    const float4 v0 = *(const float4*)&feats[base];
    const float4 v1 = *(const float4*)&feats[base + 4];
    short8v o;
    o[0] = (short)f2b(v0.x); o[1] = (short)f2b(v0.y);
    o[2] = (short)f2b(v0.z); o[3] = (short)f2b(v0.w);
    o[4] = (short)f2b(v1.x); o[5] = (short)f2b(v1.y);
    o[6] = (short)f2b(v1.z); o[7] = (short)f2b(v1.w);
    *(short8v*)&featb[base] = o;
    return;
  }

  // ---- LayerNorm + offsets
  const int lb = blk - 33 - cvtBlocks;
  const int wave = t >> 6, lane = t & 63;
  const int m = lb * 4 + wave;
  const int base = m * 256 + lane * 4;
  const float4 x = *(const float4*)&Q[base];
  float s = x.x + x.y + x.z + x.w;
  float sq = x.x * x.x + x.y * x.y + x.z * x.z + x.w * x.w;
  s = wred64(s);
  sq = wred64(sq);
  const float mu = s * (1.0f / 256.0f);
  const float var = sq * (1.0f / 256.0f) - mu * mu;
  const float rs = rsqrtf(var + 1e-5f);
  const float4 g = *(const float4*)&ln_g[lane * 4];
  const float4 bb = *(const float4*)&ln_b[lane * 4];
  float4 y;
  y.x = (x.x - mu) * rs * g.x + bb.x;
  y.y = (x.y - mu) * rs * g.y + bb.y;
  y.z = (x.z - mu) * rs * g.z + bb.z;
  y.w = (x.w - mu) * rs * g.w + bb.w;
  ushort4_t qo;
  qo.x = f2b(y.x); qo.y = f2b(y.y); qo.z = f2b(y.z); qo.w = f2b(y.w);
  *(ushort4_t*)&QNb[base] = qo;
#pragma unroll
  for (int p2 = 0; p2 < 8; ++p2) {
    const float4 w = *(const float4*)&Woff[p2 * 256 + lane * 4];
    const float o = wred64(w.x * y.x + w.y * y.y + w.z * y.z + w.w * y.w);
    if (lane == 0) OFFS[m * 8 + p2] = (o + boff[p2]) * 0.05f;
  }
}

// ---------------------------------------------------------------------------
// bf16 MFMA GEMM: Y[16384 x 256] = Xb @ Wt^T (Wt is [n][k]).
// 64x64 tiles -> 1024 blocks (4 blocks/CU). 4 waves (2x2), wave = 32x32.
// MODE 0: Y = bf16(acc + vec1[col]);  MODE 1: f32 out + resid + epilogue.
// ---------------------------------------------------------------------------
template <int MODE>
__global__ __launch_bounds__(256) void k_gemm(
    const ushort_t* __restrict__ Xb, const ushort_t* __restrict__ Wt,
    void* __restrict__ Yout, const float* __restrict__ vec1,
    const float* __restrict__ resid, const float* __restrict__ wsc,
    const float* __restrict__ beta, const float* __restrict__ bo) {
  __shared__ ushort_t As[64 * 68];
  __shared__ ushort_t Bs[64 * 68];
  __shared__ float tr[4][16 * 17];
  const int t = threadIdx.x;
  const int nb = blockIdx.x & 3, mb = blockIdx.x >> 2;
  const int m0 = mb * 64, n0 = nb * 64;
  const int wid = t >> 6, lane = t & 63;
  const int wm = wid >> 1, wn = wid & 1;
  const int lr = lane & 15, lh = lane >> 4;

  floatx4 acc[2][2];
#pragma unroll
  for (int i = 0; i < 2; ++i)
#pragma unroll
    for (int j = 0; j < 2; ++j) acc[i][j] = (floatx4){0.f, 0.f, 0.f, 0.f};

  for (int k0 = 0; k0 < 256; k0 += 64) {
#pragma unroll
    for (int q = 0; q < 2; ++q) {
      const int s = t * 2 + q;
      const int row = s >> 3;
      const int off = (s & 7) * 8;
      *(float4*)&As[row * 68 + off] =
          *(const float4*)(Xb + (size_t)(m0 + row) * 256 + k0 + off);
      *(float4*)&Bs[row * 68 + off] =
          *(const float4*)(Wt + (size_t)(n0 + row) * 256 + k0 + off);
    }
    __syncthreads();
#pragma unroll
    for (int kk = 0; kk < 64; kk += 32) {
      short8v a[2], b[2];
#pragma unroll
      for (int mi = 0; mi < 2; ++mi)
        a[mi] = *(const short8v*)&As[(wm * 32 + mi * 16 + lr) * 68 + kk + lh * 8];
#pragma unroll
      for (int ni = 0; ni < 2; ++ni)
        b[ni] = *(const short8v*)&Bs[(wn * 32 + ni * 16 + lr) * 68 + kk + lh * 8];
#pragma unroll
      for (int mi = 0; mi < 2; ++mi)
#pragma unroll
        for (int ni = 0; ni < 2; ++ni)
          acc[mi][ni] = __builtin_amdgcn_mfma_f32_16x16x32_bf16(
              a[mi], b[ni], acc[mi][ni], 0, 0, 0);
    }
    __syncthreads();
  }

  float* tb = tr[wid];
#pragma unroll
  for (int mi = 0; mi < 2; ++mi) {
#pragma unroll
    for (int ni = 0; ni < 2; ++ni) {
#pragma unroll
      for (int r = 0; r < 4; ++r)
        tb[(lh * 4 + r) * 17 + lr] = acc[mi][ni][r];
      const float4 v = *(const float4*)&tb[lr * 17 + lh * 4];
      const int row = m0 + wm * 32 + mi * 16 + lr;
      const int col = n0 + wn * 32 + ni * 16 + lh * 4;
      if (MODE == 0) {
        const float4 vc = *(const float4*)&vec1[col];
        ushort4_t o;
        o.x = f2b(v.x + vc.x);
        o.y = f2b(v.y + vc.y);
        o.z = f2b(v.z + vc.z);
        o.w = f2b(v.w + vc.w);
        *(ushort4_t*)((ushort_t*)Yout + (size_t)row * 256 + col) = o;
      } else {
        const float4 rv = *(const float4*)&resid[(size_t)row * 256 + col];
        const float4 bt = *(const float4*)&beta[col];
        const float4 bv4 = *(const float4*)&bo[col];
        const float wscale = wsc[row];
        float4 o;
        o.x = v.x + rv.x + wscale * bt.x + bv4.x;
        o.y = v.y + rv.y + wscale * bt.y + bv4.y;
        o.z = v.z + rv.z + wscale * bt.z + bv4.z;
        o.w = v.w + rv.w + wscale * bt.w + bv4.w;
        *(float4*)((float*)Yout + (size_t)row * 256 + col) = o;
      }
    }
  }
}

// ---------------------------------------------------------------------------
// Fused sampling + scores + aggregation. Wave per query; all cameras in
// registers; branchless bilinear corners; 7 interleaved butterfly reductions.
// ---------------------------------------------------------------------------
template <typename FT>
__global__ __launch_bounds__(256) void k_sample(
    const FT* __restrict__ feats, const float* __restrict__ pix,
    const int* __restrict__ vmask, const ushort_t* __restrict__ Tb,
    const ushort_t* __restrict__ QNb, const float* __restrict__ vec2,
    const float* __restrict__ bqbk, const float* __restrict__ OFFS,
    ushort_t* __restrict__ SVb, float* __restrict__ wscale) {
  const int wave = threadIdx.x >> 6, lane = threadIdx.x & 63;
  const int m = blockIdx.x * 4 + wave;
  const int b = m >> 13, n = m & 8191;

  const ushort4_t tu = *(const ushort4_t*)&Tb[(size_t)m * 256 + lane * 4];
  const float t0 = b2f(tu.x), t1 = b2f(tu.y), t2 = b2f(tu.z), t3 = b2f(tu.w);
  const ushort4_t qu = *(const ushort4_t*)&QNb[(size_t)m * 256 + lane * 4];
  const float4 v2 = *(const float4*)&vec2[lane * 4];
  const float dpg0 = v2.x * b2f(qu.x) + v2.y * b2f(qu.y) +
                     v2.z * b2f(qu.z) + v2.w * b2f(qu.w);

  float offv[8];
  {
    const float4 o0 = *(const float4*)&OFFS[m * 8];
    const float4 o1 = *(const float4*)&OFFS[m * 8 + 4];
    offv[0] = o0.x; offv[1] = o0.y; offv[2] = o0.z; offv[3] = o0.w;
    offv[4] = o1.x; offv[5] = o1.y; offv[6] = o1.z; offv[7] = o1.w;
  }
  const bool same = (offv[0] == offv[2]) && (offv[0] == offv[4]) &&
                    (offv[0] == offv[6]) && (offv[1] == offv[3]) &&
                    (offv[1] == offv[5]) && (offv[1] == offv[7]);

  int validc[6];
  float pcx[6], pcy[6];
#pragma unroll
  for (int c = 0; c < 6; ++c) {
    const int idx = (b * 6 + c) * 8192 + n;
    validc[c] = vmask[idx];
    pcx[c] = pix[(size_t)idx * 2 + 0];
    pcy[c] = pix[(size_t)idx * 2 + 1];
  }

  float4 smc[6];
#pragma unroll
  for (int c = 0; c < 6; ++c) {
    smc[c] = (float4){0.f, 0.f, 0.f, 0.f};
    if (!validc[c]) continue;
    const FT* fb = feats + (size_t)(b * 6 + c) * (HF_ * WF_ * 256);
    float4 sm = {0.f, 0.f, 0.f, 0.f};
    auto samplePoint = [&](float gx, float gy) {
      const float fx = (gx + 1.f) * 31.5f;
      const float fy = (gy + 1.f) * 31.5f;
      const float x0f = floorf(fx), y0f = floorf(fy);
      const float wx1 = fx - x0f, wx0 = 1.f - wx1;
      const float wy1 = fy - y0f, wy0 = 1.f - wy1;
      const int x0 = (int)x0f, y0 = (int)y0f;
#pragma unroll
      for (int cy = 0; cy < 2; ++cy) {
        const float yyf = y0f + (float)cy;
        const float vy = (yyf >= 0.f && yyf <= 63.f) ? 1.f : 0.f;
        const int yc = min(max(y0 + cy, 0), 63);
        const float wyv = (cy ? wy1 : wy0) * vy;
#pragma unroll
        for (int cx = 0; cx < 2; ++cx) {
          const float xxf = x0f + (float)cx;
          const float vx = (xxf >= 0.f && xxf <= 63.f) ? 1.f : 0.f;
          const int xc = min(max(x0 + cx, 0), 63);
          const float wv = wyv * (cx ? wx1 : wx0) * vx;
          const int ri = yc * WF_ + xc;
          if constexpr (sizeof(FT) == 2) {
            const ushort4_t f4 =
                *(const ushort4_t*)&fb[(size_t)ri * 256 + lane * 4];
            sm.x += wv * b2f(f4.x);
            sm.y += wv * b2f(f4.y);
            sm.z += wv * b2f(f4.z);
            sm.w += wv * b2f(f4.w);
          } else {
            const float4 f4 = *(const float4*)&fb[(size_t)ri * 256 + lane * 4];
            sm.x += wv * f4.x;
            sm.y += wv * f4.y;
            sm.z += wv * f4.z;
            sm.w += wv * f4.w;
          }
        }
      }
    };
    if (same) {
      samplePoint(pcx[c] + offv[0], pcy[c] + offv[1]);
    } else {
#pragma unroll
      for (int p = 0; p < 4; ++p)
        samplePoint(pcx[c] + offv[2 * p], pcy[c] + offv[2 * p + 1]);
      sm.x *= 0.25f; sm.y *= 0.25f; sm.z *= 0.25f; sm.w *= 0.25f;
    }
    smc[c] = sm;
  }

  // 7 interleaved butterfly reductions
  float vals[7];
  vals[0] = dpg0;
#pragma unroll
  for (int c = 0; c < 6; ++c)
    vals[1 + c] = t0 * smc[c].x + t1 * smc[c].y + t2 * smc[c].z + t3 * smc[c].w;
#pragma unroll
  for (int o = 32; o > 0; o >>= 1) {
#pragma unroll
    for (int i = 0; i < 7; ++i) vals[i] += __shfl_xor(vals[i], o, 64);
  }
  const float gam = vals[0] + bqbk[0];

  float4 sv = {0.f, 0.f, 0.f, 0.f};
  float wsum = 0.f;
  int vcnt = 0;
#pragma unroll
  for (int c = 0; c < 6; ++c) {
    if (!validc[c]) continue;
    const float w = (vals[1 + c] + gam) * (1.f / 16.f);
    sv.x += w * smc[c].x;
    sv.y += w * smc[c].y;
    sv.z += w * smc[c].z;
    sv.w += w * smc[c].w;
    wsum += w;
    ++vcnt;
  }
  const float inv = 1.f / fmaxf((float)vcnt, 1.f);
  ushort4_t o;
  o.x = f2b(sv.x * inv); o.y = f2b(sv.y * inv);
  o.z = f2b(sv.z * inv); o.w = f2b(sv.w * inv);
  *(ushort4_t*)&SVb[(size_t)m * 256 + lane * 4] = o;
  if (lane == 0) wscale[m] = wsum * inv;
}

// ---------------------------------------------------------------------------
extern "C" void kernel_launch(void* const* d_in, const int* in_sizes, int n_in,
                              void* d_out, int out_size, void* d_ws,
                              size_t ws_size, hipStream_t stream) {
  const float* queries = (const float*)d_in[0];
  const float* feats = (const float*)d_in[1];
  const float* pix = (const float*)d_in[2];
  const int* vmask = (const int*)d_in[3];
  const float* Wq = (const float*)d_in[4];
  const float* bq = (const float*)d_in[5];
  const float* Wk = (const float*)d_in[6];
  const float* bk = (const float*)d_in[7];
  const float* Wv = (const float*)d_in[8];
  const float* bv = (const float*)d_in[9];
  const float* Wo = (const float*)d_in[10];
  const float* bo = (const float*)d_in[11];
  const float* Woff = (const float*)d_in[12];
  const float* boff = (const float*)d_in[13];
  const float* ln_g = (const float*)d_in[14];
  const float* ln_b = (const float*)d_in[15];

  char* w = (char*)d_ws;
  ushort_t* At = (ushort_t*)w;   w += 256 * 256 * 2;
  ushort_t* W2t = (ushort_t*)w;  w += 256 * 256 * 2;
  float* vec1 = (float*)w;       w += 1024;
  float* vec2 = (float*)w;       w += 1024;
  float* beta = (float*)w;       w += 1024;
  float* bqbk = (float*)w;       w += 256;
  float* OFFS = (float*)w;       w += (size_t)BN_ * 8 * 4;
  float* WSC = (float*)w;        w += (size_t)BN_ * 4;
  ushort_t* QNb = (ushort_t*)w;  w += (size_t)BN_ * 256 * 2;  // SVb overlays
  ushort_t* SVb = QNb;
  ushort_t* featb = (ushort_t*)w;
  const size_t featElems = (size_t)B_ * C_ * HF_ * WF_ * 256;  // 12,582,912
  const size_t need = (size_t)(w - (char*)d_ws) + featElems * 2;
  const bool useBf16Feat = (ws_size >= need);
  const int cvtBlocks = useBf16Feat ? (int)(featElems / 2048) : 0;  // 6144

  ushort_t* Tb = (ushort_t*)d_out;  // bf16 T lives in d_out until final GEMM
  float* out = (float*)d_out;

  k_pre<<<33 + cvtBlocks + BN_ / 4, 256, 0, stream>>>(
      feats, featb, Wq, Wk, Wv, Wo, bq, bk, bv, At, W2t, vec1, vec2, beta,
      bqbk, queries, ln_g, ln_b, Woff, boff, QNb, OFFS, cvtBlocks);
  k_gemm<0><<<BN_ / 64 * 4, 256, 0, stream>>>(QNb, At, (void*)Tb, vec1,
                                              nullptr, nullptr, nullptr,
                                              nullptr);
  if (useBf16Feat)
    k_sample<ushort_t><<<BN_ / 4, 256, 0, stream>>>(
        featb, pix, vmask, Tb, QNb, vec2, bqbk, OFFS, SVb, WSC);
  else
    k_sample<float><<<BN_ / 4, 256, 0, stream>>>(
        feats, pix, vmask, Tb, QNb, vec2, bqbk, OFFS, SVb, WSC);
  k_gemm<1><<<BN_ / 64 * 4, 256, 0, stream>>>(SVb, W2t, (void*)out, nullptr,
                                              queries, WSC, beta, bo);
}